// Round 2
// baseline (1564.427 us; speedup 1.0000x reference)
//
#include <hip/hip_runtime.h>
#include <hip/hip_bf16.h>

#define HID 16
#define NGRAPH 1000
#define NEG_SLOPE 0.2f
#define EPS_GN 1e-5f

typedef __hip_bfloat16 bf16;

static __device__ __forceinline__ float b2f(bf16 v) { return __bfloat162float(v); }

struct PtrPack { const void* src[30]; int cnt[30]; int dstoff[30]; int n; };

// ---------------- dtype detection ----------------
// flags[0] = 1 if float tensors are bf16, 0 if float32
// flags[1] = 1 if edge_index is int64, 0 if int32
__global__ void detect_k(const void* x, const void* ei, int* flags) {
    __shared__ int cbf, czero;
    int t = threadIdx.x;
    if (t == 0) { cbf = 0; czero = 0; }
    __syncthreads();
    const unsigned int* xw = (const unsigned int*)x;
    unsigned int w = xw[t * 4];               // first 4KB, safe for both dtypes
    int e_lo = (int)((w >> 7) & 0xFF);        // exponent field of low-half bf16
    if (e_lo >= 100 && e_lo <= 140) atomicAdd(&cbf, 1);   // ~100% if bf16, ~16% if f32 mantissa bits
    const unsigned int* ew = (const unsigned int*)ei;
    if (ew[2 * t + 1] == 0u) atomicAdd(&czero, 1);        // all-zero odd words => int64
    __syncthreads();
    if (t == 0) {
        flags[0] = (cbf >= 192) ? 1 : 0;
        flags[1] = (czero >= 250) ? 1 : 0;
    }
}

// ---------------- convert all small params to f32 in ws ----------------
__global__ void cvt_params(PtrPack pk, const int* __restrict__ flags, float* __restrict__ dst) {
    int isb = flags[0];
    for (int j = 0; j < pk.n; ++j) {
        const void* s = pk.src[j];
        int c = pk.cnt[j], o = pk.dstoff[j];
        for (int i = threadIdx.x; i < c; i += blockDim.x) {
            float v = isb ? b2f(((const bf16*)s)[i]) : ((const float*)s)[i];
            dst[o + i] = v;
        }
    }
}

// ---------------- edge index loads (dtype-flag aware) ----------------
static __device__ __forceinline__ int ld_src(const int* ei, int E, int e, int i64) {
    return i64 ? ei[2ll * e] : ei[e];
}
static __device__ __forceinline__ int ld_dst(const int* ei, int E, int e, int i64) {
    return i64 ? ei[2ll * (E + e)] : ei[(long long)E + e];
}

// ---------------- CSR build ----------------
__global__ void hist_deg(const int* __restrict__ ei, int E, const int* __restrict__ flags,
                         int* __restrict__ deg) {
    int e = blockIdx.x * blockDim.x + threadIdx.x;
    if (e < E) atomicAdd(&deg[ld_dst(ei, E, e, flags[1])], 1);
}

__global__ void scan_bsum(const int* __restrict__ deg, int N, int* __restrict__ bsums) {
    __shared__ int sd[256];
    int t = threadIdx.x;
    int i = blockIdx.x * 256 + t;
    sd[t] = (i < N) ? deg[i] : 0;
    __syncthreads();
    for (int off = 128; off > 0; off >>= 1) {
        if (t < off) sd[t] += sd[t + off];
        __syncthreads();
    }
    if (t == 0) bsums[blockIdx.x] = sd[0];
}

__global__ void scan_top(int* __restrict__ bsums, int nb) {
    __shared__ int part[256];
    int t = threadIdx.x;
    int per = (nb + 255) >> 8;
    int lo = t * per, hi = min(lo + per, nb);
    int s = 0;
    for (int i = lo; i < hi; ++i) s += bsums[i];
    part[t] = s;
    __syncthreads();
    for (int off = 1; off < 256; off <<= 1) {
        int v = (t >= off) ? part[t - off] : 0;
        __syncthreads();
        part[t] += v;
        __syncthreads();
    }
    int acc = (t == 0) ? 0 : part[t - 1];
    for (int i = lo; i < hi; ++i) { int v = bsums[i]; bsums[i] = acc; acc += v; }
}

__global__ void scan_final(const int* __restrict__ deg, const int* __restrict__ bsums,
                           int N, int* __restrict__ rowStart) {
    __shared__ int sd[256];
    int t = threadIdx.x;
    int i = blockIdx.x * 256 + t;
    int v = (i < N) ? deg[i] : 0;
    sd[t] = v;
    __syncthreads();
    for (int off = 1; off < 256; off <<= 1) {
        int u = (t >= off) ? sd[t - off] : 0;
        __syncthreads();
        sd[t] += u;
        __syncthreads();
    }
    int incl = sd[t];
    int base = bsums[blockIdx.x];
    if (i < N) rowStart[i] = base + incl - v;
    if (i == N - 1) rowStart[N] = base + incl;
}

__global__ void scatter_csr(const int* __restrict__ ei, int E, const int* __restrict__ flags,
                            const int* __restrict__ rowStart, int* __restrict__ fill,
                            int* __restrict__ csrSrc) {
    int e = blockIdx.x * blockDim.x + threadIdx.x;
    if (e < E) {
        int i64 = flags[1];
        int d = ld_dst(ei, E, e, i64);
        int pos = rowStart[d] + atomicAdd(&fill[d], 1);
        csrSrc[pos] = ld_src(ei, E, e, i64);
    }
}

__global__ void graph_cnt_k(const int* __restrict__ batch, int N, float* __restrict__ gcnt) {
    int g = blockIdx.x * blockDim.x + threadIdx.x;
    if (g < NGRAPH) {
        int lo = 0, hi = N;
        while (lo < hi) { int mid = (lo + hi) >> 1; if (batch[mid] < g) lo = mid + 1; else hi = mid; }
        int lb = lo;
        lo = 0; hi = N;
        while (lo < hi) { int mid = (lo + hi) >> 1; if (batch[mid] <= g) lo = mid + 1; else hi = mid; }
        gcnt[g] = (float)(lo - lb);
    }
}

// ---------------- node transform: h = x@W, alpha_s, alpha_d ----------------
// prmL layout: W@0 (din*16), asrc@256, adst@272, bias@288, gw@304, gb@320, ga@336
__global__ void node_feat(const void* __restrict__ xin, int din, int isRawX,
                          const int* __restrict__ flags, const float* __restrict__ prmL,
                          float* __restrict__ h, float* __restrict__ as_, float* __restrict__ ad_,
                          int N) {
    __shared__ float sW[256], sa[HID], sd[HID];
    int t = threadIdx.x;
    if (t < din * HID) sW[t] = prmL[t];
    if (t < HID) { sa[t] = prmL[256 + t]; sd[t] = prmL[272 + t]; }
    __syncthreads();
    int i = blockIdx.x * blockDim.x + t;
    if (i >= N) return;
    int isb = isRawX ? flags[0] : 0;
    const float* xf = (const float*)xin;
    const bf16* xb = (const bf16*)xin;
    float hr[HID];
#pragma unroll
    for (int j = 0; j < HID; ++j) hr[j] = 0.f;
    int base = i * din;
    for (int k = 0; k < din; ++k) {
        float xv = isb ? b2f(xb[base + k]) : xf[base + k];
#pragma unroll
        for (int j = 0; j < HID; ++j) hr[j] = fmaf(xv, sW[k * HID + j], hr[j]);
    }
    float a1 = 0.f, a2 = 0.f;
#pragma unroll
    for (int j = 0; j < HID; ++j) { a1 = fmaf(hr[j], sa[j], a1); a2 = fmaf(hr[j], sd[j], a2); }
    float4* hp = (float4*)(h + i * HID);
#pragma unroll
    for (int q = 0; q < 4; ++q) hp[q] = make_float4(hr[q*4+0], hr[q*4+1], hr[q*4+2], hr[q*4+3]);
    as_[i] = a1; ad_[i] = a2;
}

// ---------------- GAT aggregation (16 lanes per dst node) + per-graph moment accumulation ----
__global__ void gat_agg(const int* __restrict__ rowStart, const int* __restrict__ csrSrc,
                        const float* __restrict__ h, const float* __restrict__ as_,
                        const float* __restrict__ ad_, const float* __restrict__ prmL,
                        const int* __restrict__ batch,
                        float* __restrict__ t_out, float* __restrict__ gsum,
                        float* __restrict__ gsumsq, int N) {
    __shared__ float lt[16][HID + 1];
    __shared__ int lb[16];
    int tid = threadIdx.x;
    int lane = tid & 15;
    int grp = tid >> 4;
    int node = blockIdx.x * 16 + grp;
    bool valid = node < N;
    float tval = 0.f;
    int g = -1;
    if (valid) {
        int start = rowStart[node];
        int end = rowStart[node + 1];
        float adi = ad_[node];
        float zs = as_[node] + adi;
        float e_self = zs > 0.f ? zs : NEG_SLOPE * zs;
        float mx = e_self;
        for (int base = start; base < end; base += 16) {
            int j = base + lane;
            float e = -3.4e38f;
            if (j < end) {
                float z = as_[csrSrc[j]] + adi;
                e = z > 0.f ? z : NEG_SLOPE * z;
            }
            mx = fmaxf(mx, e);
        }
#pragma unroll
        for (int off = 1; off < 16; off <<= 1) mx = fmaxf(mx, __shfl_xor(mx, off, 64));
        float ssum = 0.f, acc = 0.f;
        for (int base = start; base < end; base += 16) {
            int j = base + lane;
            float p = 0.f;
            int sidx = 0;
            if (j < end) {
                sidx = csrSrc[j];
                float z = as_[sidx] + adi;
                z = z > 0.f ? z : NEG_SLOPE * z;
                p = __expf(z - mx);
            }
            ssum += p;
            int cnt = min(16, end - base);
            for (int k = 0; k < cnt; ++k) {
                float pk = __shfl(p, k, 16);
                int sk = __shfl(sidx, k, 16);
                acc = fmaf(pk, h[(sk << 4) + lane], acc);
            }
        }
#pragma unroll
        for (int off = 1; off < 16; off <<= 1) ssum += __shfl_xor(ssum, off, 64);
        float pself = __expf(e_self - mx);
        ssum += pself;
        acc = fmaf(pself, h[(node << 4) + lane], acc);
        tval = acc / ssum + prmL[288 + lane];
        t_out[(node << 4) + lane] = tval;
        g = batch[node];
    }
    if (lane == 0) lb[grp] = valid ? g : -1;
    lt[grp][lane] = tval;
    __syncthreads();
    if (tid < HID) {
        int f = tid;
        float s1 = 0.f, s2 = 0.f;
        int cur = -2;
        for (int n = 0; n < 16; ++n) {
            int bg = lb[n];
            if (bg < 0) continue;
            if (bg != cur) {
                if (cur >= 0) { atomicAdd(&gsum[cur * HID + f], s1); atomicAdd(&gsumsq[cur * HID + f], s2); }
                cur = bg; s1 = 0.f; s2 = 0.f;
            }
            float v = lt[n][f];
            s1 += v; s2 += v * v;
        }
        if (cur >= 0) { atomicAdd(&gsum[cur * HID + f], s1); atomicAdd(&gsumsq[cur * HID + f], s2); }
    }
}

// ---------------- GraphNorm coefficients ----------------
__global__ void norm_coef(const float* __restrict__ gsum, const float* __restrict__ gsumsq,
                          const float* __restrict__ gcnt, const float* __restrict__ prmL,
                          float* __restrict__ A, float* __restrict__ B) {
    int idx = blockIdx.x * blockDim.x + threadIdx.x;
    if (idx < NGRAPH * HID) {
        int g = idx >> 4, f = idx & 15;
        float c = gcnt[g];
        float invc = c > 0.f ? 1.f / c : 0.f;
        float mean = gsum[idx] * invc;
        float msq = gsumsq[idx] * invc;
        float gaf = prmL[336 + f];
        float var = msq + (gaf * gaf - 2.f * gaf) * mean * mean;
        var = fmaxf(var, 0.f);
        float inv = rsqrtf(var + EPS_GN);
        float Af = prmL[304 + f] * inv;
        A[idx] = Af;
        B[idx] = prmL[320 + f] - Af * gaf * mean;
    }
}

// ---------------- apply norm + relu (+residual) (+pool last layer) ----------------
__global__ void apply_norm(const float* __restrict__ t_in, const float* __restrict__ A,
                           const float* __restrict__ B, const int* __restrict__ batch,
                           float* __restrict__ xcur, int N, int residual,
                           float* __restrict__ pooled) {
    __shared__ float lt[16][HID + 1];
    __shared__ int lb[16];
    int tid = threadIdx.x;
    int idx = blockIdx.x * 256 + tid;
    int node = idx >> 4;
    int f = idx & 15;
    int grp = tid >> 4;
    float v = 0.f;
    int g = -1;
    if (node < N) {
        g = batch[node];
        v = A[g * HID + f] * t_in[idx] + B[g * HID + f];
        if (residual) v += xcur[idx];
        v = fmaxf(v, 0.f);
        xcur[idx] = v;
    }
    if (pooled) {
        if ((tid & 15) == 0) lb[grp] = (node < N) ? g : -1;
        lt[grp][f] = v;
        __syncthreads();
        if (tid < HID) {
            float s1 = 0.f;
            int cur = -2;
            for (int n = 0; n < 16; ++n) {
                int bg = lb[n];
                if (bg < 0) continue;
                if (bg != cur) { if (cur >= 0) atomicAdd(&pooled[cur * HID + tid], s1); cur = bg; s1 = 0.f; }
                s1 += lt[n][tid];
            }
            if (cur >= 0) atomicAdd(&pooled[cur * HID + tid], s1);
        }
    }
}

// ---------------- final linear (dtype-flag output) ----------------
__global__ void final_lin(const float* __restrict__ pooled, const float* __restrict__ gcnt,
                          const float* __restrict__ prm, const int* __restrict__ flags,
                          void* __restrict__ out) {
    int g = blockIdx.x * blockDim.x + threadIdx.x;
    if (g < NGRAPH) {
        float c = gcnt[g];
        float invc = c > 0.f ? 1.f / c : 0.f;
        float o0 = prm[1440], o1 = prm[1441];
#pragma unroll
        for (int f = 0; f < HID; ++f) {
            float p = pooled[g * HID + f] * invc;
            o0 = fmaf(p, prm[1408 + f * 2 + 0], o0);
            o1 = fmaf(p, prm[1408 + f * 2 + 1], o1);
        }
        if (flags[0]) {
            ((bf16*)out)[g * 2 + 0] = __float2bfloat16(o0);
            ((bf16*)out)[g * 2 + 1] = __float2bfloat16(o1);
        } else {
            ((float*)out)[g * 2 + 0] = o0;
            ((float*)out)[g * 2 + 1] = o1;
        }
    }
}

extern "C" void kernel_launch(void* const* d_in, const int* in_sizes, int n_in,
                              void* d_out, int out_size, void* d_ws, size_t ws_size,
                              hipStream_t stream) {
    const void* x = d_in[0];
    const int* ei = (const int*)d_in[1];
    const int* batch = (const int*)d_in[2];
    int N = in_sizes[2];
    int E = in_sizes[1] / 2;
    int din0 = in_sizes[0] / N;

    // workspace layout
    float* ws = (float*)d_ws;
    int* flags = (int*)ws;                          // 16 ints (use 2)
    float* prm = ws + 16;                           // 2048 floats of converted params
    float* h = ws + 4096;                           // N*16
    float* t = h + (size_t)N * HID;                 // N*16
    float* xcur = t + (size_t)N * HID;              // N*16
    float* as_ = xcur + (size_t)N * HID;            // N
    float* ad_ = as_ + N;                           // N
    int* deg = (int*)(ad_ + N);                     // N
    int* fill = deg + N;                            // N
    int* rowStart = fill + N;                       // N+1
    int* bsums = rowStart + (N + 1);                // 2048
    int* csrSrc = bsums + 2048;                     // E
    float* gsum = (float*)(csrSrc + E);             // G*16
    float* gsumsq = gsum + NGRAPH * HID;
    float* gA = gsumsq + NGRAPH * HID;
    float* gB = gA + NGRAPH * HID;
    float* pooled = gB + NGRAPH * HID;
    float* gcnt = pooled + NGRAPH * HID;

    // param pack: per layer W, asrc, adst, b, gw, gb, ga; then lin_w, lin_b
    PtrPack pk;
    int n = 0;
    for (int l = 0; l < 4; ++l) {
        int dl = (l == 0) ? din0 : HID;
        int base = l * 352;
        const int offs[7] = {0, 256, 272, 288, 304, 320, 336};
        const int cnts[7] = {dl * HID, HID, HID, HID, HID, HID, HID};
        for (int j = 0; j < 7; ++j) {
            pk.src[n] = d_in[4 + l * 7 + j];
            pk.cnt[n] = cnts[j];
            pk.dstoff[n] = base + offs[j];
            ++n;
        }
    }
    pk.src[n] = d_in[32]; pk.cnt[n] = HID * 2; pk.dstoff[n] = 1408; ++n;
    pk.src[n] = d_in[33]; pk.cnt[n] = 2;       pk.dstoff[n] = 1440; ++n;
    pk.n = n;

    int nbN = (N + 255) / 256;
    int nbE = (E + 255) / 256;

    detect_k<<<1, 256, 0, stream>>>(x, ei, flags);
    cvt_params<<<1, 256, 0, stream>>>(pk, flags, prm);

    hipMemsetAsync(deg, 0, (size_t)N * 2 * sizeof(int), stream);      // deg + fill
    hipMemsetAsync(pooled, 0, NGRAPH * HID * sizeof(float), stream);

    hist_deg<<<nbE, 256, 0, stream>>>(ei, E, flags, deg);
    scan_bsum<<<nbN, 256, 0, stream>>>(deg, N, bsums);
    scan_top<<<1, 256, 0, stream>>>(bsums, nbN);
    scan_final<<<nbN, 256, 0, stream>>>(deg, bsums, N, rowStart);
    scatter_csr<<<nbE, 256, 0, stream>>>(ei, E, flags, rowStart, fill, csrSrc);
    graph_cnt_k<<<(NGRAPH + 255) / 256, 256, 0, stream>>>(batch, N, gcnt);

    int aggBlocks = (N + 15) / 16;
    int applyBlocks = (int)(((size_t)N * HID + 255) / 256);

    for (int l = 0; l < 4; ++l) {
        const float* prmL = prm + l * 352;
        if (l == 0)
            node_feat<<<nbN, 256, 0, stream>>>(x, din0, 1, flags, prmL, h, as_, ad_, N);
        else
            node_feat<<<nbN, 256, 0, stream>>>(xcur, HID, 0, flags, prmL, h, as_, ad_, N);

        hipMemsetAsync(gsum, 0, 2 * NGRAPH * HID * sizeof(float), stream);
        gat_agg<<<aggBlocks, 256, 0, stream>>>(rowStart, csrSrc, h, as_, ad_, prmL, batch,
                                               t, gsum, gsumsq, N);
        norm_coef<<<(NGRAPH * HID + 255) / 256, 256, 0, stream>>>(gsum, gsumsq, gcnt, prmL, gA, gB);
        apply_norm<<<applyBlocks, 256, 0, stream>>>(t, gA, gB, batch, xcur, N, l > 0 ? 1 : 0,
                                                    l == 3 ? pooled : (float*)nullptr);
    }

    final_lin<<<(NGRAPH + 255) / 256, 256, 0, stream>>>(pooled, gcnt, prm, flags, d_out);
}

// Round 3
// 1551.693 us; speedup vs baseline: 1.0082x; 1.0082x over previous
//
#include <hip/hip_runtime.h>
#include <hip/hip_bf16.h>

#define HID 16
#define NGRAPH 1000
#define NEG_SLOPE 0.2f
#define EPS_GN 1e-5f

typedef __hip_bfloat16 bf16;

static __device__ __forceinline__ float b2f(bf16 v) { return __bfloat162float(v); }

struct PtrPack { const void* src[30]; int cnt[30]; int dstoff[30]; int n; };

// ---------------- dtype detection ----------------
__global__ void detect_k(const void* x, const void* ei, int* flags) {
    __shared__ int cbf, czero;
    int t = threadIdx.x;
    if (t == 0) { cbf = 0; czero = 0; }
    __syncthreads();
    const unsigned int* xw = (const unsigned int*)x;
    unsigned int w = xw[t * 4];
    int e_lo = (int)((w >> 7) & 0xFF);
    if (e_lo >= 100 && e_lo <= 140) atomicAdd(&cbf, 1);
    const unsigned int* ew = (const unsigned int*)ei;
    if (ew[2 * t + 1] == 0u) atomicAdd(&czero, 1);
    __syncthreads();
    if (t == 0) {
        flags[0] = (cbf >= 192) ? 1 : 0;
        flags[1] = (czero >= 250) ? 1 : 0;
    }
}

__global__ void cvt_params(PtrPack pk, const int* __restrict__ flags, float* __restrict__ dst) {
    int isb = flags[0];
    for (int j = 0; j < pk.n; ++j) {
        const void* s = pk.src[j];
        int c = pk.cnt[j], o = pk.dstoff[j];
        for (int i = threadIdx.x; i < c; i += blockDim.x) {
            float v = isb ? b2f(((const bf16*)s)[i]) : ((const float*)s)[i];
            dst[o + i] = v;
        }
    }
}

static __device__ __forceinline__ int ld_src(const int* ei, int E, int e, int i64) {
    return i64 ? ei[2ll * e] : ei[e];
}
static __device__ __forceinline__ int ld_dst(const int* ei, int E, int e, int i64) {
    return i64 ? ei[2ll * (E + e)] : ei[(long long)E + e];
}

// ---------------- CSR build ----------------
__global__ void hist_deg(const int* __restrict__ ei, int E, const int* __restrict__ flags,
                         int* __restrict__ deg) {
    int e = blockIdx.x * blockDim.x + threadIdx.x;
    if (e < E) atomicAdd(&deg[ld_dst(ei, E, e, flags[1])], 1);
}

__global__ void scan_bsum(const int* __restrict__ deg, int N, int* __restrict__ bsums) {
    __shared__ int sd[256];
    int t = threadIdx.x;
    int i = blockIdx.x * 256 + t;
    sd[t] = (i < N) ? deg[i] : 0;
    __syncthreads();
    for (int off = 128; off > 0; off >>= 1) {
        if (t < off) sd[t] += sd[t + off];
        __syncthreads();
    }
    if (t == 0) bsums[blockIdx.x] = sd[0];
}

__global__ void scan_top(int* __restrict__ bsums, int nb) {
    __shared__ int part[256];
    int t = threadIdx.x;
    int per = (nb + 255) >> 8;
    int lo = t * per, hi = min(lo + per, nb);
    int s = 0;
    for (int i = lo; i < hi; ++i) s += bsums[i];
    part[t] = s;
    __syncthreads();
    for (int off = 1; off < 256; off <<= 1) {
        int v = (t >= off) ? part[t - off] : 0;
        __syncthreads();
        part[t] += v;
        __syncthreads();
    }
    int acc = (t == 0) ? 0 : part[t - 1];
    for (int i = lo; i < hi; ++i) { int v = bsums[i]; bsums[i] = acc; acc += v; }
}

__global__ void scan_final(const int* __restrict__ deg, const int* __restrict__ bsums,
                           int N, int* __restrict__ rowStart, int* __restrict__ cursor) {
    __shared__ int sd[256];
    int t = threadIdx.x;
    int i = blockIdx.x * 256 + t;
    int v = (i < N) ? deg[i] : 0;
    sd[t] = v;
    __syncthreads();
    for (int off = 1; off < 256; off <<= 1) {
        int u = (t >= off) ? sd[t - off] : 0;
        __syncthreads();
        sd[t] += u;
        __syncthreads();
    }
    int incl = sd[t];
    int base = bsums[blockIdx.x];
    if (i < N) { int rs = base + incl - v; rowStart[i] = rs; cursor[i] = rs; }
    if (i == N - 1) rowStart[N] = base + incl;
}

__global__ void scatter_csr(const int* __restrict__ ei, int E, const int* __restrict__ flags,
                            int* __restrict__ cursor, int* __restrict__ csrSrc) {
    int e = blockIdx.x * blockDim.x + threadIdx.x;
    if (e < E) {
        int i64 = flags[1];
        int d = ld_dst(ei, E, e, i64);
        int pos = atomicAdd(&cursor[d], 1);
        csrSrc[pos] = ld_src(ei, E, e, i64);
    }
}

__global__ void graph_cnt_k(const int* __restrict__ batch, int N, float* __restrict__ gcnt) {
    int g = blockIdx.x * blockDim.x + threadIdx.x;
    if (g < NGRAPH) {
        int lo = 0, hi = N;
        while (lo < hi) { int mid = (lo + hi) >> 1; if (batch[mid] < g) lo = mid + 1; else hi = mid; }
        int lb = lo;
        lo = 0; hi = N;
        while (lo < hi) { int mid = (lo + hi) >> 1; if (batch[mid] <= g) lo = mid + 1; else hi = mid; }
        gcnt[g] = (float)(lo - lb);
    }
}

// ---------------- layer-0 node transform: h = x@W1, alpha_s, alpha_d ----------------
__global__ void node_feat0(const void* __restrict__ xin, int din,
                           const int* __restrict__ flags, const float* __restrict__ prmL,
                           float* __restrict__ h, float* __restrict__ as_, float* __restrict__ ad_,
                           int N) {
    __shared__ float sW[256], sa[HID], sd[HID];
    int t = threadIdx.x;
    if (t < din * HID) sW[t] = prmL[t];
    if (t < HID) { sa[t] = prmL[256 + t]; sd[t] = prmL[272 + t]; }
    __syncthreads();
    int i = blockIdx.x * blockDim.x + t;
    if (i >= N) return;
    int isb = flags[0];
    const float* xf = (const float*)xin;
    const bf16* xb = (const bf16*)xin;
    float hr[HID];
#pragma unroll
    for (int j = 0; j < HID; ++j) hr[j] = 0.f;
    int base = i * din;
    for (int k = 0; k < din; ++k) {
        float xv = isb ? b2f(xb[base + k]) : xf[base + k];
#pragma unroll
        for (int j = 0; j < HID; ++j) hr[j] = fmaf(xv, sW[k * HID + j], hr[j]);
    }
    float a1 = 0.f, a2 = 0.f;
#pragma unroll
    for (int j = 0; j < HID; ++j) { a1 = fmaf(hr[j], sa[j], a1); a2 = fmaf(hr[j], sd[j], a2); }
    float4* hp = (float4*)(h + i * HID);
#pragma unroll
    for (int q = 0; q < 4; ++q) hp[q] = make_float4(hr[q*4+0], hr[q*4+1], hr[q*4+2], hr[q*4+3]);
    as_[i] = a1; ad_[i] = a2;
}

// ---------------- GAT aggregation, single-pass online softmax ----------------
__global__ void gat_agg(const int* __restrict__ rowStart, const int* __restrict__ csrSrc,
                        const float* __restrict__ h, const float* __restrict__ as_,
                        const float* __restrict__ ad_, const float* __restrict__ prmL,
                        const int* __restrict__ batch,
                        float* __restrict__ t_out, float* __restrict__ gsum,
                        float* __restrict__ gsumsq, int N) {
    __shared__ float lt[16][HID + 1];
    __shared__ int lb[16];
    int tid = threadIdx.x;
    int lane = tid & 15;
    int grp = tid >> 4;
    int node = blockIdx.x * 16 + grp;
    bool valid = node < N;
    float tval = 0.f;
    int g = -1;
    if (valid) {
        int start = rowStart[node];
        int end = rowStart[node + 1];
        float adi = ad_[node];
        float hself = h[(node << 4) + lane];
        float zs = as_[node] + adi;
        float e_self = zs > 0.f ? zs : NEG_SLOPE * zs;
        float m = e_self, ssum = 0.f, acc = 0.f;
        for (int base = start; base < end; base += 16) {
            int j = base + lane;
            int sidx = (j < end) ? csrSrc[j] : 0;
            float e = -1e30f;
            if (j < end) {
                float z = as_[sidx] + adi;
                e = z > 0.f ? z : NEG_SLOPE * z;
            }
            float cm = e;
#pragma unroll
            for (int off = 1; off < 16; off <<= 1) cm = fmaxf(cm, __shfl_xor(cm, off, 64));
            if (cm > m) {
                float sc = __expf(m - cm);
                ssum *= sc; acc *= sc; m = cm;
            }
            float p = (j < end) ? __expf(e - m) : 0.f;
            ssum += p;
            int cnt = min(16, end - base);
            for (int k = 0; k < cnt; ++k) {
                float pk = __shfl(p, k, 16);
                int sk = __shfl(sidx, k, 16);
                acc = fmaf(pk, h[(sk << 4) + lane], acc);
            }
        }
#pragma unroll
        for (int off = 1; off < 16; off <<= 1) ssum += __shfl_xor(ssum, off, 64);
        float pself = __expf(e_self - m);   // <= 1 since m >= e_self
        ssum += pself;
        acc = fmaf(pself, hself, acc);
        tval = acc / ssum + prmL[288 + lane];
        t_out[(node << 4) + lane] = tval;
        g = batch[node];
    }
    if (lane == 0) lb[grp] = valid ? g : -1;
    lt[grp][lane] = tval;
    __syncthreads();
    if (tid < HID) {
        int f = tid;
        float s1 = 0.f, s2 = 0.f;
        int cur = -2;
        for (int n = 0; n < 16; ++n) {
            int bg = lb[n];
            if (bg < 0) continue;
            if (bg != cur) {
                if (cur >= 0) { atomicAdd(&gsum[cur * HID + f], s1); atomicAdd(&gsumsq[cur * HID + f], s2); }
                cur = bg; s1 = 0.f; s2 = 0.f;
            }
            float v = lt[n][f];
            s1 += v; s2 += v * v;
        }
        if (cur >= 0) { atomicAdd(&gsum[cur * HID + f], s1); atomicAdd(&gsumsq[cur * HID + f], s2); }
    }
}

// ---------------- GraphNorm coefficients ----------------
__global__ void norm_coef(const float* __restrict__ gsum, const float* __restrict__ gsumsq,
                          const float* __restrict__ gcnt, const float* __restrict__ prmL,
                          float* __restrict__ A, float* __restrict__ B) {
    int idx = blockIdx.x * blockDim.x + threadIdx.x;
    if (idx < NGRAPH * HID) {
        int g = idx >> 4, f = idx & 15;
        float c = gcnt[g];
        float invc = c > 0.f ? 1.f / c : 0.f;
        float mean = gsum[idx] * invc;
        float msq = gsumsq[idx] * invc;
        float gaf = prmL[336 + f];
        float var = msq + (gaf * gaf - 2.f * gaf) * mean * mean;
        var = fmaxf(var, 0.f);
        float inv = rsqrtf(var + EPS_GN);
        float Af = prmL[304 + f] * inv;
        A[idx] = Af;
        B[idx] = prmL[320 + f] - Af * gaf * mean;
    }
}

// ---------------- fused: apply norm+relu(+residual), then next layer's features ----------------
// non-last: xcur = relu(A*t+B [+xcur]); h = xcur@Wnext; as_, ad_.
// last:     v = relu(A*t+B + xcur); pooled[g] += v (run-length LDS aggregation).
__global__ void norm_feat(const float* __restrict__ t_in, const float* __restrict__ gA,
                          const float* __restrict__ gB, const int* __restrict__ batch,
                          float* __restrict__ xcur, int N, int residual, int isLast,
                          const float* __restrict__ prmNext,
                          float* __restrict__ h, float* __restrict__ as_, float* __restrict__ ad_,
                          float* __restrict__ pooled) {
    __shared__ float sW[256], sa[HID], sd[HID];
    __shared__ float sv[256][HID + 1];
    __shared__ int sg[256];
    int tid = threadIdx.x;
    if (!isLast) {
        sW[tid] = prmNext[tid];
        if (tid < HID) { sa[tid] = prmNext[256 + tid]; sd[tid] = prmNext[272 + tid]; }
        __syncthreads();
    }
    int i = blockIdx.x * 256 + tid;
    float v[HID];
    int g = -1;
    if (i < N) {
        g = batch[i];
        const float* Ar = gA + g * HID;
        const float* Br = gB + g * HID;
        const float4* tp = (const float4*)(t_in + (i << 4));
        float4 xr[4];
        if (residual) {
            const float4* xp = (const float4*)(xcur + (i << 4));
#pragma unroll
            for (int q = 0; q < 4; ++q) xr[q] = xp[q];
        } else {
#pragma unroll
            for (int q = 0; q < 4; ++q) xr[q] = make_float4(0.f, 0.f, 0.f, 0.f);
        }
#pragma unroll
        for (int q = 0; q < 4; ++q) {
            float4 t4 = tp[q];
            float ts[4] = {t4.x, t4.y, t4.z, t4.w};
            float xs[4] = {xr[q].x, xr[q].y, xr[q].z, xr[q].w};
#pragma unroll
            for (int c = 0; c < 4; ++c) {
                int f = q * 4 + c;
                float val = fmaf(Ar[f], ts[c], Br[f]) + xs[c];
                v[f] = fmaxf(val, 0.f);
            }
        }
    }
    if (isLast) {
        sg[tid] = (i < N) ? g : -1;
#pragma unroll
        for (int f = 0; f < HID; ++f) sv[tid][f] = (i < N) ? v[f] : 0.f;
        __syncthreads();
        if (tid < HID) {
            int f = tid;
            float s1 = 0.f;
            int cur = -2;
            for (int n = 0; n < 256; ++n) {
                int bg = sg[n];
                if (bg < 0) continue;
                if (bg != cur) { if (cur >= 0) atomicAdd(&pooled[cur * HID + f], s1); cur = bg; s1 = 0.f; }
                s1 += sv[n][f];
            }
            if (cur >= 0) atomicAdd(&pooled[cur * HID + f], s1);
        }
    } else if (i < N) {
        float4* xp = (float4*)(xcur + (i << 4));
#pragma unroll
        for (int q = 0; q < 4; ++q) xp[q] = make_float4(v[q*4+0], v[q*4+1], v[q*4+2], v[q*4+3]);
        float hr[HID];
#pragma unroll
        for (int j = 0; j < HID; ++j) hr[j] = 0.f;
#pragma unroll
        for (int k = 0; k < HID; ++k) {
            float xv = v[k];
#pragma unroll
            for (int j = 0; j < HID; ++j) hr[j] = fmaf(xv, sW[k * HID + j], hr[j]);
        }
        float a1 = 0.f, a2 = 0.f;
#pragma unroll
        for (int j = 0; j < HID; ++j) { a1 = fmaf(hr[j], sa[j], a1); a2 = fmaf(hr[j], sd[j], a2); }
        float4* hp = (float4*)(h + (i << 4));
#pragma unroll
        for (int q = 0; q < 4; ++q) hp[q] = make_float4(hr[q*4+0], hr[q*4+1], hr[q*4+2], hr[q*4+3]);
        as_[i] = a1; ad_[i] = a2;
    }
}

// ---------------- final linear ----------------
__global__ void final_lin(const float* __restrict__ pooled, const float* __restrict__ gcnt,
                          const float* __restrict__ prm, const int* __restrict__ flags,
                          void* __restrict__ out) {
    int g = blockIdx.x * blockDim.x + threadIdx.x;
    if (g < NGRAPH) {
        float c = gcnt[g];
        float invc = c > 0.f ? 1.f / c : 0.f;
        float o0 = prm[1440], o1 = prm[1441];
#pragma unroll
        for (int f = 0; f < HID; ++f) {
            float p = pooled[g * HID + f] * invc;
            o0 = fmaf(p, prm[1408 + f * 2 + 0], o0);
            o1 = fmaf(p, prm[1408 + f * 2 + 1], o1);
        }
        if (flags[0]) {
            ((bf16*)out)[g * 2 + 0] = __float2bfloat16(o0);
            ((bf16*)out)[g * 2 + 1] = __float2bfloat16(o1);
        } else {
            ((float*)out)[g * 2 + 0] = o0;
            ((float*)out)[g * 2 + 1] = o1;
        }
    }
}

extern "C" void kernel_launch(void* const* d_in, const int* in_sizes, int n_in,
                              void* d_out, int out_size, void* d_ws, size_t ws_size,
                              hipStream_t stream) {
    const void* x = d_in[0];
    const int* ei = (const int*)d_in[1];
    const int* batch = (const int*)d_in[2];
    int N = in_sizes[2];
    int E = in_sizes[1] / 2;
    int din0 = in_sizes[0] / N;

    float* ws = (float*)d_ws;
    int* flags = (int*)ws;                          // 16 ints
    float* prm = ws + 16;                           // 2048 floats
    float* h = ws + 4096;                           // N*16
    float* t = h + (size_t)N * HID;                 // N*16
    float* xcur = t + (size_t)N * HID;              // N*16
    float* as_ = xcur + (size_t)N * HID;            // N
    float* ad_ = as_ + N;                           // N
    int* deg = (int*)(ad_ + N);                     // N
    int* cursor = deg + N;                          // N
    int* rowStart = cursor + N;                     // N+1
    int* bsums = rowStart + (N + 1);                // 2048
    int* csrSrc = bsums + 2048;                     // E
    float* gsum = (float*)(csrSrc + E);             // G*16
    float* gsumsq = gsum + NGRAPH * HID;
    float* gA = gsumsq + NGRAPH * HID;
    float* gB = gA + NGRAPH * HID;
    float* pooled = gB + NGRAPH * HID;
    float* gcnt = pooled + NGRAPH * HID;

    PtrPack pk;
    int n = 0;
    for (int l = 0; l < 4; ++l) {
        int dl = (l == 0) ? din0 : HID;
        int base = l * 352;
        const int offs[7] = {0, 256, 272, 288, 304, 320, 336};
        const int cnts[7] = {dl * HID, HID, HID, HID, HID, HID, HID};
        for (int j = 0; j < 7; ++j) {
            pk.src[n] = d_in[4 + l * 7 + j];
            pk.cnt[n] = cnts[j];
            pk.dstoff[n] = base + offs[j];
            ++n;
        }
    }
    pk.src[n] = d_in[32]; pk.cnt[n] = HID * 2; pk.dstoff[n] = 1408; ++n;
    pk.src[n] = d_in[33]; pk.cnt[n] = 2;       pk.dstoff[n] = 1440; ++n;
    pk.n = n;

    int nbN = (N + 255) / 256;
    int nbE = (E + 255) / 256;

    detect_k<<<1, 256, 0, stream>>>(x, ei, flags);
    cvt_params<<<1, 256, 0, stream>>>(pk, flags, prm);

    hipMemsetAsync(deg, 0, (size_t)N * sizeof(int), stream);
    hipMemsetAsync(pooled, 0, NGRAPH * HID * sizeof(float), stream);

    hist_deg<<<nbE, 256, 0, stream>>>(ei, E, flags, deg);
    scan_bsum<<<nbN, 256, 0, stream>>>(deg, N, bsums);
    scan_top<<<1, 256, 0, stream>>>(bsums, nbN);
    scan_final<<<nbN, 256, 0, stream>>>(deg, bsums, N, rowStart, cursor);
    scatter_csr<<<nbE, 256, 0, stream>>>(ei, E, flags, cursor, csrSrc);
    graph_cnt_k<<<(NGRAPH + 255) / 256, 256, 0, stream>>>(batch, N, gcnt);

    node_feat0<<<nbN, 256, 0, stream>>>(x, din0, flags, prm, h, as_, ad_, N);

    int aggBlocks = (N + 15) / 16;

    for (int l = 0; l < 4; ++l) {
        const float* prmL = prm + l * 352;
        const float* prmNext = prm + (l + 1 < 4 ? (l + 1) * 352 : 0);

        hipMemsetAsync(gsum, 0, 2 * NGRAPH * HID * sizeof(float), stream);
        gat_agg<<<aggBlocks, 256, 0, stream>>>(rowStart, csrSrc, h, as_, ad_, prmL, batch,
                                               t, gsum, gsumsq, N);
        norm_coef<<<(NGRAPH * HID + 255) / 256, 256, 0, stream>>>(gsum, gsumsq, gcnt, prmL, gA, gB);
        norm_feat<<<nbN, 256, 0, stream>>>(t, gA, gB, batch, xcur, N, l > 0 ? 1 : 0,
                                           l == 3 ? 1 : 0, prmNext, h, as_, ad_, pooled);
    }

    final_lin<<<(NGRAPH + 255) / 256, 256, 0, stream>>>(pooled, gcnt, prm, flags, d_out);
}

// Round 4
// 1395.738 us; speedup vs baseline: 1.1209x; 1.1117x over previous
//
#include <hip/hip_runtime.h>
#include <hip/hip_bf16.h>

#define HID 16
#define NGRAPH 1000
#define NEG_SLOPE 0.2f
#define EPS_GN 1e-5f

typedef __hip_bfloat16 bf16;

static __device__ __forceinline__ float b2f(bf16 v) { return __bfloat162float(v); }

struct PtrPack { const void* src[30]; int cnt[30]; int dstoff[30]; int n; };

// ---------------- dtype detection ----------------
__global__ void detect_k(const void* x, const void* ei, int* flags) {
    __shared__ int cbf, czero;
    int t = threadIdx.x;
    if (t == 0) { cbf = 0; czero = 0; }
    __syncthreads();
    const unsigned int* xw = (const unsigned int*)x;
    unsigned int w = xw[t * 4];
    int e_lo = (int)((w >> 7) & 0xFF);
    if (e_lo >= 100 && e_lo <= 140) atomicAdd(&cbf, 1);
    const unsigned int* ew = (const unsigned int*)ei;
    if (ew[2 * t + 1] == 0u) atomicAdd(&czero, 1);
    __syncthreads();
    if (t == 0) {
        flags[0] = (cbf >= 192) ? 1 : 0;
        flags[1] = (czero >= 250) ? 1 : 0;
    }
}

__global__ void cvt_params(PtrPack pk, const int* __restrict__ flags, float* __restrict__ dst) {
    int isb = flags[0];
    for (int j = 0; j < pk.n; ++j) {
        const void* s = pk.src[j];
        int c = pk.cnt[j], o = pk.dstoff[j];
        for (int i = threadIdx.x; i < c; i += blockDim.x) {
            float v = isb ? b2f(((const bf16*)s)[i]) : ((const float*)s)[i];
            dst[o + i] = v;
        }
    }
}

static __device__ __forceinline__ int ld_src(const int* ei, int E, int e, int i64) {
    return i64 ? ei[2ll * e] : ei[e];
}
static __device__ __forceinline__ int ld_dst(const int* ei, int E, int e, int i64) {
    return i64 ? ei[2ll * (E + e)] : ei[(long long)E + e];
}

// ---------------- CSR build ----------------
// Phase 1: degree count + per-edge sequence number (coalesced store, atomic return used
// only for the coalesced seq write — random store moved to `place`).
__global__ void hist_pos(const int* __restrict__ ei, int E, const int* __restrict__ flags,
                         int* __restrict__ deg, int* __restrict__ seq) {
    int e = blockIdx.x * blockDim.x + threadIdx.x;
    if (e < E) {
        int d = ld_dst(ei, E, e, flags[1]);
        seq[e] = atomicAdd(&deg[d], 1);
    }
}

__global__ void scan_bsum(const int* __restrict__ deg, int N, int* __restrict__ bsums) {
    __shared__ int sd[256];
    int t = threadIdx.x;
    int i = blockIdx.x * 256 + t;
    sd[t] = (i < N) ? deg[i] : 0;
    __syncthreads();
    for (int off = 128; off > 0; off >>= 1) {
        if (t < off) sd[t] += sd[t + off];
        __syncthreads();
    }
    if (t == 0) bsums[blockIdx.x] = sd[0];
}

__global__ void scan_top(int* __restrict__ bsums, int nb) {
    __shared__ int part[256];
    int t = threadIdx.x;
    int per = (nb + 255) >> 8;
    int lo = t * per, hi = min(lo + per, nb);
    int s = 0;
    for (int i = lo; i < hi; ++i) s += bsums[i];
    part[t] = s;
    __syncthreads();
    for (int off = 1; off < 256; off <<= 1) {
        int v = (t >= off) ? part[t - off] : 0;
        __syncthreads();
        part[t] += v;
        __syncthreads();
    }
    int acc = (t == 0) ? 0 : part[t - 1];
    for (int i = lo; i < hi; ++i) { int v = bsums[i]; bsums[i] = acc; acc += v; }
}

__global__ void scan_final(const int* __restrict__ deg, const int* __restrict__ bsums,
                           int N, int* __restrict__ rowStart) {
    __shared__ int sd[256];
    int t = threadIdx.x;
    int i = blockIdx.x * 256 + t;
    int v = (i < N) ? deg[i] : 0;
    sd[t] = v;
    __syncthreads();
    for (int off = 1; off < 256; off <<= 1) {
        int u = (t >= off) ? sd[t - off] : 0;
        __syncthreads();
        sd[t] += u;
        __syncthreads();
    }
    int incl = sd[t];
    int base = bsums[blockIdx.x];
    if (i < N) rowStart[i] = base + incl - v;
    if (i == N - 1) rowStart[N] = base + incl;
}

// Phase 2: placement. All loads coalesced (rowStart gather is L2-resident 2MB);
// the random store has no atomic dependency — fire-and-forget.
__global__ void place(const int* __restrict__ ei, int E, const int* __restrict__ flags,
                      const int* __restrict__ rowStart, const int* __restrict__ seq,
                      int* __restrict__ csrSrc) {
    int e = blockIdx.x * blockDim.x + threadIdx.x;
    if (e < E) {
        int i64 = flags[1];
        int d = ld_dst(ei, E, e, i64);
        int s = ld_src(ei, E, e, i64);
        csrSrc[rowStart[d] + seq[e]] = s;
    }
}

__global__ void graph_cnt_k(const int* __restrict__ batch, int N, float* __restrict__ gcnt) {
    int g = blockIdx.x * blockDim.x + threadIdx.x;
    if (g < NGRAPH) {
        int lo = 0, hi = N;
        while (lo < hi) { int mid = (lo + hi) >> 1; if (batch[mid] < g) lo = mid + 1; else hi = mid; }
        int lb = lo;
        lo = 0; hi = N;
        while (lo < hi) { int mid = (lo + hi) >> 1; if (batch[mid] <= g) lo = mid + 1; else hi = mid; }
        gcnt[g] = (float)(lo - lb);
    }
}

// ---------------- layer-0 node transform ----------------
__global__ void node_feat0(const void* __restrict__ xin, int din,
                           const int* __restrict__ flags, const float* __restrict__ prmL,
                           float* __restrict__ h, float* __restrict__ as_, float* __restrict__ ad_,
                           int N) {
    __shared__ float sW[256], sa[HID], sd[HID];
    int t = threadIdx.x;
    if (t < din * HID) sW[t] = prmL[t];
    if (t < HID) { sa[t] = prmL[256 + t]; sd[t] = prmL[272 + t]; }
    __syncthreads();
    int i = blockIdx.x * blockDim.x + t;
    if (i >= N) return;
    int isb = flags[0];
    const float* xf = (const float*)xin;
    const bf16* xb = (const bf16*)xin;
    float hr[HID];
#pragma unroll
    for (int j = 0; j < HID; ++j) hr[j] = 0.f;
    int base = i * din;
    for (int k = 0; k < din; ++k) {
        float xv = isb ? b2f(xb[base + k]) : xf[base + k];
#pragma unroll
        for (int j = 0; j < HID; ++j) hr[j] = fmaf(xv, sW[k * HID + j], hr[j]);
    }
    float a1 = 0.f, a2 = 0.f;
#pragma unroll
    for (int j = 0; j < HID; ++j) { a1 = fmaf(hr[j], sa[j], a1); a2 = fmaf(hr[j], sd[j], a2); }
    float4* hp = (float4*)(h + i * HID);
#pragma unroll
    for (int q = 0; q < 4; ++q) hp[q] = make_float4(hr[q*4+0], hr[q*4+1], hr[q*4+2], hr[q*4+3]);
    as_[i] = a1; ad_[i] = a2;
}

// ---------------- GAT aggregation: one lane per node, scalar online softmax ----------------
// block = 256 threads = 256 consecutive nodes; t writes coalesced; per-graph moments via
// LDS run-length aggregation (batch sorted). h[src] gather = one 64B line per edge.
__global__ void gat_agg(const int* __restrict__ rowStart, const int* __restrict__ csrSrc,
                        const float* __restrict__ h, const float* __restrict__ as_,
                        const float* __restrict__ ad_, const float* __restrict__ prmL,
                        const int* __restrict__ batch,
                        float* __restrict__ t_out, float* __restrict__ gsum,
                        float* __restrict__ gsumsq, int N) {
    __shared__ float sv[256][HID + 1];
    __shared__ int sg[256];
    int tid = threadIdx.x;
    int node = blockIdx.x * 256 + tid;
    bool valid = node < N;
    float acc[HID];
    float tv[HID];
    int g = -1;
    if (valid) {
        int start = rowStart[node];
        int end = rowStart[node + 1];
        float adi = ad_[node];
        const float4* hp = (const float4*)(h + (node << 4));
        float4 hs0 = hp[0], hs1 = hp[1], hs2 = hp[2], hs3 = hp[3];
        float zs = as_[node] + adi;
        float e_self = zs > 0.f ? zs : NEG_SLOPE * zs;
        float m = e_self, ssum = 0.f;
#pragma unroll
        for (int f = 0; f < HID; ++f) acc[f] = 0.f;
        for (int j = start; j < end; ++j) {
            int s = csrSrc[j];
            float z = as_[s] + adi;
            float e = z > 0.f ? z : NEG_SLOPE * z;
            if (e > m) {
                float sc = __expf(m - e);
                ssum *= sc;
#pragma unroll
                for (int f = 0; f < HID; ++f) acc[f] *= sc;
                m = e;
            }
            float p = __expf(e - m);
            ssum += p;
            const float4* hq = (const float4*)(h + (s << 4));
            float4 q0 = hq[0], q1 = hq[1], q2 = hq[2], q3 = hq[3];
            acc[0] = fmaf(p, q0.x, acc[0]);  acc[1] = fmaf(p, q0.y, acc[1]);
            acc[2] = fmaf(p, q0.z, acc[2]);  acc[3] = fmaf(p, q0.w, acc[3]);
            acc[4] = fmaf(p, q1.x, acc[4]);  acc[5] = fmaf(p, q1.y, acc[5]);
            acc[6] = fmaf(p, q1.z, acc[6]);  acc[7] = fmaf(p, q1.w, acc[7]);
            acc[8] = fmaf(p, q2.x, acc[8]);  acc[9] = fmaf(p, q2.y, acc[9]);
            acc[10] = fmaf(p, q2.z, acc[10]); acc[11] = fmaf(p, q2.w, acc[11]);
            acc[12] = fmaf(p, q3.x, acc[12]); acc[13] = fmaf(p, q3.y, acc[13]);
            acc[14] = fmaf(p, q3.z, acc[14]); acc[15] = fmaf(p, q3.w, acc[15]);
        }
        float pself = __expf(e_self - m);
        ssum += pself;
        acc[0] = fmaf(pself, hs0.x, acc[0]);  acc[1] = fmaf(pself, hs0.y, acc[1]);
        acc[2] = fmaf(pself, hs0.z, acc[2]);  acc[3] = fmaf(pself, hs0.w, acc[3]);
        acc[4] = fmaf(pself, hs1.x, acc[4]);  acc[5] = fmaf(pself, hs1.y, acc[5]);
        acc[6] = fmaf(pself, hs1.z, acc[6]);  acc[7] = fmaf(pself, hs1.w, acc[7]);
        acc[8] = fmaf(pself, hs2.x, acc[8]);  acc[9] = fmaf(pself, hs2.y, acc[9]);
        acc[10] = fmaf(pself, hs2.z, acc[10]); acc[11] = fmaf(pself, hs2.w, acc[11]);
        acc[12] = fmaf(pself, hs3.x, acc[12]); acc[13] = fmaf(pself, hs3.y, acc[13]);
        acc[14] = fmaf(pself, hs3.z, acc[14]); acc[15] = fmaf(pself, hs3.w, acc[15]);
        float inv = 1.f / ssum;
#pragma unroll
        for (int f = 0; f < HID; ++f) tv[f] = fmaf(acc[f], inv, prmL[288 + f]);
        float4* tp = (float4*)(t_out + (node << 4));
        tp[0] = make_float4(tv[0], tv[1], tv[2], tv[3]);
        tp[1] = make_float4(tv[4], tv[5], tv[6], tv[7]);
        tp[2] = make_float4(tv[8], tv[9], tv[10], tv[11]);
        tp[3] = make_float4(tv[12], tv[13], tv[14], tv[15]);
        g = batch[node];
    }
    sg[tid] = valid ? g : -1;
#pragma unroll
    for (int f = 0; f < HID; ++f) sv[tid][f] = valid ? tv[f] : 0.f;
    __syncthreads();
    // 64 threads: 4 segments of 64 nodes × 16 features, run-length aggregation
    if (tid < 64) {
        int f = tid & 15;
        int seg = tid >> 4;
        int n0 = seg * 64, n1 = n0 + 64;
        float s1 = 0.f, s2 = 0.f;
        int cur = -2;
        for (int n = n0; n < n1; ++n) {
            int bg = sg[n];
            if (bg < 0) continue;
            if (bg != cur) {
                if (cur >= 0) { atomicAdd(&gsum[cur * HID + f], s1); atomicAdd(&gsumsq[cur * HID + f], s2); }
                cur = bg; s1 = 0.f; s2 = 0.f;
            }
            float v = sv[n][f];
            s1 += v; s2 += v * v;
        }
        if (cur >= 0) { atomicAdd(&gsum[cur * HID + f], s1); atomicAdd(&gsumsq[cur * HID + f], s2); }
    }
}

// ---------------- GraphNorm coefficients ----------------
__global__ void norm_coef(const float* __restrict__ gsum, const float* __restrict__ gsumsq,
                          const float* __restrict__ gcnt, const float* __restrict__ prmL,
                          float* __restrict__ A, float* __restrict__ B) {
    int idx = blockIdx.x * blockDim.x + threadIdx.x;
    if (idx < NGRAPH * HID) {
        int g = idx >> 4, f = idx & 15;
        float c = gcnt[g];
        float invc = c > 0.f ? 1.f / c : 0.f;
        float mean = gsum[idx] * invc;
        float msq = gsumsq[idx] * invc;
        float gaf = prmL[336 + f];
        float var = msq + (gaf * gaf - 2.f * gaf) * mean * mean;
        var = fmaxf(var, 0.f);
        float inv = rsqrtf(var + EPS_GN);
        float Af = prmL[304 + f] * inv;
        A[idx] = Af;
        B[idx] = prmL[320 + f] - Af * gaf * mean;
    }
}

// ---------------- fused norm+relu(+residual) + next-layer features / final pool ----------------
__global__ void norm_feat(const float* __restrict__ t_in, const float* __restrict__ gA,
                          const float* __restrict__ gB, const int* __restrict__ batch,
                          float* __restrict__ xcur, int N, int residual, int isLast,
                          const float* __restrict__ prmNext,
                          float* __restrict__ h, float* __restrict__ as_, float* __restrict__ ad_,
                          float* __restrict__ pooled) {
    __shared__ float sW[256], sa[HID], sd[HID];
    __shared__ float sv[256][HID + 1];
    __shared__ int sg[256];
    int tid = threadIdx.x;
    if (!isLast) {
        sW[tid] = prmNext[tid];
        if (tid < HID) { sa[tid] = prmNext[256 + tid]; sd[tid] = prmNext[272 + tid]; }
        __syncthreads();
    }
    int i = blockIdx.x * 256 + tid;
    float v[HID];
    int g = -1;
    if (i < N) {
        g = batch[i];
        const float* Ar = gA + g * HID;
        const float* Br = gB + g * HID;
        const float4* tp = (const float4*)(t_in + (i << 4));
        float4 xr[4];
        if (residual) {
            const float4* xp = (const float4*)(xcur + (i << 4));
#pragma unroll
            for (int q = 0; q < 4; ++q) xr[q] = xp[q];
        } else {
#pragma unroll
            for (int q = 0; q < 4; ++q) xr[q] = make_float4(0.f, 0.f, 0.f, 0.f);
        }
#pragma unroll
        for (int q = 0; q < 4; ++q) {
            float4 t4 = tp[q];
            float ts[4] = {t4.x, t4.y, t4.z, t4.w};
            float xs[4] = {xr[q].x, xr[q].y, xr[q].z, xr[q].w};
#pragma unroll
            for (int c = 0; c < 4; ++c) {
                int f = q * 4 + c;
                float val = fmaf(Ar[f], ts[c], Br[f]) + xs[c];
                v[f] = fmaxf(val, 0.f);
            }
        }
    }
    if (isLast) {
        sg[tid] = (i < N) ? g : -1;
#pragma unroll
        for (int f = 0; f < HID; ++f) sv[tid][f] = (i < N) ? v[f] : 0.f;
        __syncthreads();
        if (tid < 64) {
            int f = tid & 15;
            int seg = tid >> 4;
            int n0 = seg * 64, n1 = n0 + 64;
            float s1 = 0.f;
            int cur = -2;
            for (int n = n0; n < n1; ++n) {
                int bg = sg[n];
                if (bg < 0) continue;
                if (bg != cur) { if (cur >= 0) atomicAdd(&pooled[cur * HID + f], s1); cur = bg; s1 = 0.f; }
                s1 += sv[n][f];
            }
            if (cur >= 0) atomicAdd(&pooled[cur * HID + f], s1);
        }
    } else if (i < N) {
        float4* xp = (float4*)(xcur + (i << 4));
#pragma unroll
        for (int q = 0; q < 4; ++q) xp[q] = make_float4(v[q*4+0], v[q*4+1], v[q*4+2], v[q*4+3]);
        float hr[HID];
#pragma unroll
        for (int j = 0; j < HID; ++j) hr[j] = 0.f;
#pragma unroll
        for (int k = 0; k < HID; ++k) {
            float xv = v[k];
#pragma unroll
            for (int j = 0; j < HID; ++j) hr[j] = fmaf(xv, sW[k * HID + j], hr[j]);
        }
        float a1 = 0.f, a2 = 0.f;
#pragma unroll
        for (int j = 0; j < HID; ++j) { a1 = fmaf(hr[j], sa[j], a1); a2 = fmaf(hr[j], sd[j], a2); }
        float4* hp = (float4*)(h + (i << 4));
#pragma unroll
        for (int q = 0; q < 4; ++q) hp[q] = make_float4(hr[q*4+0], hr[q*4+1], hr[q*4+2], hr[q*4+3]);
        as_[i] = a1; ad_[i] = a2;
    }
}

// ---------------- final linear ----------------
__global__ void final_lin(const float* __restrict__ pooled, const float* __restrict__ gcnt,
                          const float* __restrict__ prm, const int* __restrict__ flags,
                          void* __restrict__ out) {
    int g = blockIdx.x * blockDim.x + threadIdx.x;
    if (g < NGRAPH) {
        float c = gcnt[g];
        float invc = c > 0.f ? 1.f / c : 0.f;
        float o0 = prm[1440], o1 = prm[1441];
#pragma unroll
        for (int f = 0; f < HID; ++f) {
            float p = pooled[g * HID + f] * invc;
            o0 = fmaf(p, prm[1408 + f * 2 + 0], o0);
            o1 = fmaf(p, prm[1408 + f * 2 + 1], o1);
        }
        if (flags[0]) {
            ((bf16*)out)[g * 2 + 0] = __float2bfloat16(o0);
            ((bf16*)out)[g * 2 + 1] = __float2bfloat16(o1);
        } else {
            ((float*)out)[g * 2 + 0] = o0;
            ((float*)out)[g * 2 + 1] = o1;
        }
    }
}

extern "C" void kernel_launch(void* const* d_in, const int* in_sizes, int n_in,
                              void* d_out, int out_size, void* d_ws, size_t ws_size,
                              hipStream_t stream) {
    const void* x = d_in[0];
    const int* ei = (const int*)d_in[1];
    const int* batch = (const int*)d_in[2];
    int N = in_sizes[2];
    int E = in_sizes[1] / 2;
    int din0 = in_sizes[0] / N;

    float* ws = (float*)d_ws;
    int* flags = (int*)ws;                          // 16 ints
    float* prm = ws + 16;                           // 2048 floats
    float* h = ws + 4096;                           // N*16
    float* t = h + (size_t)N * HID;                 // N*16
    float* xcur = t + (size_t)N * HID;              // N*16
    float* as_ = xcur + (size_t)N * HID;            // N
    float* ad_ = as_ + N;                           // N
    int* deg = (int*)(ad_ + N);                     // N
    int* rowStart = deg + N;                        // N+1
    int* bsums = rowStart + (N + 1);                // 2048
    int* csrSrc = bsums + 2048;                     // E (+pad)
    float* gsum = (float*)(csrSrc + E + 64);        // G*16
    float* gsumsq = gsum + NGRAPH * HID;
    float* gA = gsumsq + NGRAPH * HID;
    float* gB = gA + NGRAPH * HID;
    float* pooled = gB + NGRAPH * HID;
    float* gcnt = pooled + NGRAPH * HID;
    int* seq = (int*)h;                             // aliased: consumed by `place` before node_feat0

    PtrPack pk;
    int n = 0;
    for (int l = 0; l < 4; ++l) {
        int dl = (l == 0) ? din0 : HID;
        int base = l * 352;
        const int offs[7] = {0, 256, 272, 288, 304, 320, 336};
        const int cnts[7] = {dl * HID, HID, HID, HID, HID, HID, HID};
        for (int j = 0; j < 7; ++j) {
            pk.src[n] = d_in[4 + l * 7 + j];
            pk.cnt[n] = cnts[j];
            pk.dstoff[n] = base + offs[j];
            ++n;
        }
    }
    pk.src[n] = d_in[32]; pk.cnt[n] = HID * 2; pk.dstoff[n] = 1408; ++n;
    pk.src[n] = d_in[33]; pk.cnt[n] = 2;       pk.dstoff[n] = 1440; ++n;
    pk.n = n;

    int nbN = (N + 255) / 256;
    int nbE = (E + 255) / 256;

    detect_k<<<1, 256, 0, stream>>>(x, ei, flags);
    cvt_params<<<1, 256, 0, stream>>>(pk, flags, prm);

    hipMemsetAsync(deg, 0, (size_t)N * sizeof(int), stream);
    hipMemsetAsync(pooled, 0, NGRAPH * HID * sizeof(float), stream);

    hist_pos<<<nbE, 256, 0, stream>>>(ei, E, flags, deg, seq);
    scan_bsum<<<nbN, 256, 0, stream>>>(deg, N, bsums);
    scan_top<<<1, 256, 0, stream>>>(bsums, nbN);
    scan_final<<<nbN, 256, 0, stream>>>(deg, bsums, N, rowStart);
    place<<<nbE, 256, 0, stream>>>(ei, E, flags, rowStart, seq, csrSrc);
    graph_cnt_k<<<(NGRAPH + 255) / 256, 256, 0, stream>>>(batch, N, gcnt);

    node_feat0<<<nbN, 256, 0, stream>>>(x, din0, flags, prm, h, as_, ad_, N);

    for (int l = 0; l < 4; ++l) {
        const float* prmL = prm + l * 352;
        const float* prmNext = prm + (l + 1 < 4 ? (l + 1) * 352 : 0);

        hipMemsetAsync(gsum, 0, 2 * NGRAPH * HID * sizeof(float), stream);
        gat_agg<<<nbN, 256, 0, stream>>>(rowStart, csrSrc, h, as_, ad_, prmL, batch,
                                         t, gsum, gsumsq, N);
        norm_coef<<<(NGRAPH * HID + 255) / 256, 256, 0, stream>>>(gsum, gsumsq, gcnt, prmL, gA, gB);
        norm_feat<<<nbN, 256, 0, stream>>>(t, gA, gB, batch, xcur, N, l > 0 ? 1 : 0,
                                           l == 3 ? 1 : 0, prmNext, h, as_, ad_, pooled);
    }

    final_lin<<<(NGRAPH + 255) / 256, 256, 0, stream>>>(pooled, gcnt, prm, flags, d_out);
}

// Round 5
// 1210.304 us; speedup vs baseline: 1.2926x; 1.1532x over previous
//
#include <hip/hip_runtime.h>
#include <hip/hip_bf16.h>

#define HID 16
#define NGRAPH 1000
#define NEG_SLOPE 0.2f
#define EPS_GN 1e-5f

typedef __hip_bfloat16 bf16;

static __device__ __forceinline__ float b2f(bf16 v) { return __bfloat162float(v); }

// pack two floats into one u32 holding two RNE-rounded bf16s (a=low, b=high)
static __device__ __forceinline__ unsigned int pack2(float a, float b) {
    unsigned int ia = __float_as_uint(a);
    unsigned int ib = __float_as_uint(b);
    ia += 0x7FFFu + ((ia >> 16) & 1u);
    ib += 0x7FFFu + ((ib >> 16) & 1u);
    return (ia >> 16) | (ib & 0xFFFF0000u);
}

// acc[0..15] += p * bf16row(ra,rb)
static __device__ __forceinline__ void fma_row(const uint4 ra, const uint4 rb, float p,
                                               float* __restrict__ acc) {
    unsigned int us[8] = {ra.x, ra.y, ra.z, ra.w, rb.x, rb.y, rb.z, rb.w};
#pragma unroll
    for (int q = 0; q < 8; ++q) {
        float lo = __uint_as_float(us[q] << 16);
        float hi = __uint_as_float(us[q] & 0xFFFF0000u);
        acc[2 * q]     = fmaf(p, lo, acc[2 * q]);
        acc[2 * q + 1] = fmaf(p, hi, acc[2 * q + 1]);
    }
}

struct PtrPack { const void* src[30]; int cnt[30]; int dstoff[30]; int n; };

// ---------------- dtype detection ----------------
__global__ void detect_k(const void* x, const void* ei, int* flags) {
    __shared__ int cbf, czero;
    int t = threadIdx.x;
    if (t == 0) { cbf = 0; czero = 0; }
    __syncthreads();
    const unsigned int* xw = (const unsigned int*)x;
    unsigned int w = xw[t * 4];
    int e_lo = (int)((w >> 7) & 0xFF);
    if (e_lo >= 100 && e_lo <= 140) atomicAdd(&cbf, 1);
    const unsigned int* ew = (const unsigned int*)ei;
    if (ew[2 * t + 1] == 0u) atomicAdd(&czero, 1);
    __syncthreads();
    if (t == 0) {
        flags[0] = (cbf >= 192) ? 1 : 0;
        flags[1] = (czero >= 250) ? 1 : 0;
    }
}

__global__ void cvt_params(PtrPack pk, const int* __restrict__ flags, float* __restrict__ dst) {
    int isb = flags[0];
    for (int j = 0; j < pk.n; ++j) {
        const void* s = pk.src[j];
        int c = pk.cnt[j], o = pk.dstoff[j];
        for (int i = threadIdx.x; i < c; i += blockDim.x) {
            float v = isb ? b2f(((const bf16*)s)[i]) : ((const float*)s)[i];
            dst[o + i] = v;
        }
    }
}

static __device__ __forceinline__ int ld_src(const int* ei, int E, int e, int i64) {
    return i64 ? ei[2ll * e] : ei[e];
}
static __device__ __forceinline__ int ld_dst(const int* ei, int E, int e, int i64) {
    return i64 ? ei[2ll * (E + e)] : ei[(long long)E + e];
}

// ---------------- CSR build ----------------
__global__ void hist_pos(const int* __restrict__ ei, int E, const int* __restrict__ flags,
                         int* __restrict__ deg, int* __restrict__ seq) {
    int e = blockIdx.x * blockDim.x + threadIdx.x;
    if (e < E) {
        int d = ld_dst(ei, E, e, flags[1]);
        seq[e] = atomicAdd(&deg[d], 1);
    }
}

__global__ void scan_bsum(const int* __restrict__ deg, int N, int* __restrict__ bsums) {
    __shared__ int sd[256];
    int t = threadIdx.x;
    int i = blockIdx.x * 256 + t;
    sd[t] = (i < N) ? deg[i] : 0;
    __syncthreads();
    for (int off = 128; off > 0; off >>= 1) {
        if (t < off) sd[t] += sd[t + off];
        __syncthreads();
    }
    if (t == 0) bsums[blockIdx.x] = sd[0];
}

__global__ void scan_top(int* __restrict__ bsums, int nb) {
    __shared__ int part[256];
    int t = threadIdx.x;
    int per = (nb + 255) >> 8;
    int lo = t * per, hi = min(lo + per, nb);
    int s = 0;
    for (int i = lo; i < hi; ++i) s += bsums[i];
    part[t] = s;
    __syncthreads();
    for (int off = 1; off < 256; off <<= 1) {
        int v = (t >= off) ? part[t - off] : 0;
        __syncthreads();
        part[t] += v;
        __syncthreads();
    }
    int acc = (t == 0) ? 0 : part[t - 1];
    for (int i = lo; i < hi; ++i) { int v = bsums[i]; bsums[i] = acc; acc += v; }
}

__global__ void scan_final(const int* __restrict__ deg, const int* __restrict__ bsums,
                           int N, int* __restrict__ rowStart) {
    __shared__ int sd[256];
    int t = threadIdx.x;
    int i = blockIdx.x * 256 + t;
    int v = (i < N) ? deg[i] : 0;
    sd[t] = v;
    __syncthreads();
    for (int off = 1; off < 256; off <<= 1) {
        int u = (t >= off) ? sd[t - off] : 0;
        __syncthreads();
        sd[t] += u;
        __syncthreads();
    }
    int incl = sd[t];
    int base = bsums[blockIdx.x];
    if (i < N) rowStart[i] = base + incl - v;
    if (i == N - 1) rowStart[N] = base + incl;
}

__global__ void place(const int* __restrict__ ei, int E, const int* __restrict__ flags,
                      const int* __restrict__ rowStart, const int* __restrict__ seq,
                      int* __restrict__ csrSrc) {
    int e = blockIdx.x * blockDim.x + threadIdx.x;
    if (e < E) {
        int i64 = flags[1];
        int d = ld_dst(ei, E, e, i64);
        int s = ld_src(ei, E, e, i64);
        csrSrc[rowStart[d] + seq[e]] = s;
    }
}

__global__ void graph_cnt_k(const int* __restrict__ batch, int N, float* __restrict__ gcnt) {
    int g = blockIdx.x * blockDim.x + threadIdx.x;
    if (g < NGRAPH) {
        int lo = 0, hi = N;
        while (lo < hi) { int mid = (lo + hi) >> 1; if (batch[mid] < g) lo = mid + 1; else hi = mid; }
        int lb = lo;
        lo = 0; hi = N;
        while (lo < hi) { int mid = (lo + hi) >> 1; if (batch[mid] <= g) lo = mid + 1; else hi = mid; }
        gcnt[g] = (float)(lo - lb);
    }
}

// ---------------- layer-0 node transform (writes bf16-packed h) ----------------
__global__ void node_feat0(const void* __restrict__ xin, int din,
                           const int* __restrict__ flags, const float* __restrict__ prmL,
                           unsigned int* __restrict__ hb, float* __restrict__ as_,
                           float* __restrict__ ad_, int N) {
    __shared__ float sW[256], sa[HID], sd[HID];
    int t = threadIdx.x;
    if (t < din * HID) sW[t] = prmL[t];
    if (t < HID) { sa[t] = prmL[256 + t]; sd[t] = prmL[272 + t]; }
    __syncthreads();
    int i = blockIdx.x * blockDim.x + t;
    if (i >= N) return;
    int isb = flags[0];
    const float* xf = (const float*)xin;
    const bf16* xb = (const bf16*)xin;
    float hr[HID];
#pragma unroll
    for (int j = 0; j < HID; ++j) hr[j] = 0.f;
    int base = i * din;
    for (int k = 0; k < din; ++k) {
        float xv = isb ? b2f(xb[base + k]) : xf[base + k];
#pragma unroll
        for (int j = 0; j < HID; ++j) hr[j] = fmaf(xv, sW[k * HID + j], hr[j]);
    }
    float a1 = 0.f, a2 = 0.f;
#pragma unroll
    for (int j = 0; j < HID; ++j) { a1 = fmaf(hr[j], sa[j], a1); a2 = fmaf(hr[j], sd[j], a2); }
    uint4* hp = (uint4*)(hb + (i << 3));
    uint4 w0, w1;
    w0.x = pack2(hr[0], hr[1]);   w0.y = pack2(hr[2], hr[3]);
    w0.z = pack2(hr[4], hr[5]);   w0.w = pack2(hr[6], hr[7]);
    w1.x = pack2(hr[8], hr[9]);   w1.y = pack2(hr[10], hr[11]);
    w1.z = pack2(hr[12], hr[13]); w1.w = pack2(hr[14], hr[15]);
    hp[0] = w0; hp[1] = w1;
    as_[i] = a1; ad_[i] = a2;
}

// ---------------- GAT aggregation: lane-per-node, chunk-4 MLP, bf16 h gathers ----------------
__global__ void __launch_bounds__(256, 4)
gat_agg(const int* __restrict__ rowStart, const int* __restrict__ csrSrc,
        const unsigned int* __restrict__ hb, const float* __restrict__ as_,
        const float* __restrict__ ad_, const float* __restrict__ prmL,
        const int* __restrict__ batch,
        float* __restrict__ t_out, float* __restrict__ gsum,
        float* __restrict__ gsumsq, int N) {
    __shared__ float sv[256][HID + 1];
    __shared__ int sg[256];
    int tid = threadIdx.x;
    int node = blockIdx.x * 256 + tid;
    bool valid = node < N;
    float acc[HID];
    float tv[HID];
    int g = -1;
    if (valid) {
        int start = rowStart[node];
        int end = rowStart[node + 1];
        float adi = ad_[node];
        float zs = as_[node] + adi;
        float e_self = zs > 0.f ? zs : NEG_SLOPE * zs;
        float m = e_self, ssum = 0.f;
#pragma unroll
        for (int f = 0; f < HID; ++f) acc[f] = 0.f;
        for (int base = start; base < end; base += 4) {
            bool v1 = base + 1 < end, v2 = base + 2 < end, v3 = base + 3 < end;
            int s0 = csrSrc[base];
            int s1 = v1 ? csrSrc[base + 1] : s0;
            int s2 = v2 ? csrSrc[base + 2] : s0;
            int s3 = v3 ? csrSrc[base + 3] : s0;
            // independent alpha gathers
            float a0 = as_[s0], a1 = as_[s1], a2 = as_[s2], a3 = as_[s3];
            // independent h-row gathers (issued before they're needed)
            const uint4* h0 = (const uint4*)(hb + (s0 << 3));
            const uint4* h1 = (const uint4*)(hb + (s1 << 3));
            const uint4* h2 = (const uint4*)(hb + (s2 << 3));
            const uint4* h3 = (const uint4*)(hb + (s3 << 3));
            uint4 r00 = h0[0], r01 = h0[1];
            uint4 r10 = h1[0], r11 = h1[1];
            uint4 r20 = h2[0], r21 = h2[1];
            uint4 r30 = h3[0], r31 = h3[1];
            float z0 = a0 + adi, z1 = a1 + adi, z2 = a2 + adi, z3 = a3 + adi;
            float e0 = z0 > 0.f ? z0 : NEG_SLOPE * z0;
            float e1 = v1 ? (z1 > 0.f ? z1 : NEG_SLOPE * z1) : -1e30f;
            float e2 = v2 ? (z2 > 0.f ? z2 : NEG_SLOPE * z2) : -1e30f;
            float e3 = v3 ? (z3 > 0.f ? z3 : NEG_SLOPE * z3) : -1e30f;
            float cm = fmaxf(fmaxf(e0, e1), fmaxf(e2, e3));
            if (cm > m) {
                float sc = __expf(m - cm);
                ssum *= sc;
#pragma unroll
                for (int f = 0; f < HID; ++f) acc[f] *= sc;
                m = cm;
            }
            float p0 = __expf(e0 - m);
            float p1 = v1 ? __expf(e1 - m) : 0.f;
            float p2 = v2 ? __expf(e2 - m) : 0.f;
            float p3 = v3 ? __expf(e3 - m) : 0.f;
            ssum += p0 + p1 + p2 + p3;
            fma_row(r00, r01, p0, acc);
            fma_row(r10, r11, p1, acc);
            fma_row(r20, r21, p2, acc);
            fma_row(r30, r31, p3, acc);
        }
        const uint4* hs = (const uint4*)(hb + (node << 3));
        uint4 rs0 = hs[0], rs1 = hs[1];
        float pself = __expf(e_self - m);
        ssum += pself;
        fma_row(rs0, rs1, pself, acc);
        float inv = 1.f / ssum;
#pragma unroll
        for (int f = 0; f < HID; ++f) tv[f] = fmaf(acc[f], inv, prmL[288 + f]);
        float4* tp = (float4*)(t_out + (node << 4));
        tp[0] = make_float4(tv[0], tv[1], tv[2], tv[3]);
        tp[1] = make_float4(tv[4], tv[5], tv[6], tv[7]);
        tp[2] = make_float4(tv[8], tv[9], tv[10], tv[11]);
        tp[3] = make_float4(tv[12], tv[13], tv[14], tv[15]);
        g = batch[node];
    }
    sg[tid] = valid ? g : -1;
#pragma unroll
    for (int f = 0; f < HID; ++f) sv[tid][f] = valid ? tv[f] : 0.f;
    __syncthreads();
    if (tid < 64) {
        int f = tid & 15;
        int seg = tid >> 4;
        int n0 = seg * 64, n1 = n0 + 64;
        float s1 = 0.f, s2 = 0.f;
        int cur = -2;
        for (int n = n0; n < n1; ++n) {
            int bg = sg[n];
            if (bg < 0) continue;
            if (bg != cur) {
                if (cur >= 0) { atomicAdd(&gsum[cur * HID + f], s1); atomicAdd(&gsumsq[cur * HID + f], s2); }
                cur = bg; s1 = 0.f; s2 = 0.f;
            }
            float v = sv[n][f];
            s1 += v; s2 += v * v;
        }
        if (cur >= 0) { atomicAdd(&gsum[cur * HID + f], s1); atomicAdd(&gsumsq[cur * HID + f], s2); }
    }
}

// ---------------- GraphNorm coefficients ----------------
__global__ void norm_coef(const float* __restrict__ gsum, const float* __restrict__ gsumsq,
                          const float* __restrict__ gcnt, const float* __restrict__ prmL,
                          float* __restrict__ A, float* __restrict__ B) {
    int idx = blockIdx.x * blockDim.x + threadIdx.x;
    if (idx < NGRAPH * HID) {
        int g = idx >> 4, f = idx & 15;
        float c = gcnt[g];
        float invc = c > 0.f ? 1.f / c : 0.f;
        float mean = gsum[idx] * invc;
        float msq = gsumsq[idx] * invc;
        float gaf = prmL[336 + f];
        float var = msq + (gaf * gaf - 2.f * gaf) * mean * mean;
        var = fmaxf(var, 0.f);
        float inv = rsqrtf(var + EPS_GN);
        float Af = prmL[304 + f] * inv;
        A[idx] = Af;
        B[idx] = prmL[320 + f] - Af * gaf * mean;
    }
}

// ---------------- fused norm+relu(+residual) + next-layer features / final pool ----------------
__global__ void norm_feat(const float* __restrict__ t_in, const float* __restrict__ gA,
                          const float* __restrict__ gB, const int* __restrict__ batch,
                          float* __restrict__ xcur, int N, int residual, int isLast,
                          const float* __restrict__ prmNext,
                          unsigned int* __restrict__ hb, float* __restrict__ as_,
                          float* __restrict__ ad_, float* __restrict__ pooled) {
    __shared__ float sW[256], sa[HID], sd[HID];
    __shared__ float sv[256][HID + 1];
    __shared__ int sg[256];
    int tid = threadIdx.x;
    if (!isLast) {
        sW[tid] = prmNext[tid];
        if (tid < HID) { sa[tid] = prmNext[256 + tid]; sd[tid] = prmNext[272 + tid]; }
        __syncthreads();
    }
    int i = blockIdx.x * 256 + tid;
    float v[HID];
    int g = -1;
    if (i < N) {
        g = batch[i];
        const float* Ar = gA + g * HID;
        const float* Br = gB + g * HID;
        const float4* tp = (const float4*)(t_in + (i << 4));
        float4 xr[4];
        if (residual) {
            const float4* xp = (const float4*)(xcur + (i << 4));
#pragma unroll
            for (int q = 0; q < 4; ++q) xr[q] = xp[q];
        } else {
#pragma unroll
            for (int q = 0; q < 4; ++q) xr[q] = make_float4(0.f, 0.f, 0.f, 0.f);
        }
#pragma unroll
        for (int q = 0; q < 4; ++q) {
            float4 t4 = tp[q];
            float ts[4] = {t4.x, t4.y, t4.z, t4.w};
            float xs[4] = {xr[q].x, xr[q].y, xr[q].z, xr[q].w};
#pragma unroll
            for (int c = 0; c < 4; ++c) {
                int f = q * 4 + c;
                float val = fmaf(Ar[f], ts[c], Br[f]) + xs[c];
                v[f] = fmaxf(val, 0.f);
            }
        }
    }
    if (isLast) {
        sg[tid] = (i < N) ? g : -1;
#pragma unroll
        for (int f = 0; f < HID; ++f) sv[tid][f] = (i < N) ? v[f] : 0.f;
        __syncthreads();
        if (tid < 64) {
            int f = tid & 15;
            int seg = tid >> 4;
            int n0 = seg * 64, n1 = n0 + 64;
            float s1 = 0.f;
            int cur = -2;
            for (int n = n0; n < n1; ++n) {
                int bg = sg[n];
                if (bg < 0) continue;
                if (bg != cur) { if (cur >= 0) atomicAdd(&pooled[cur * HID + f], s1); cur = bg; s1 = 0.f; }
                s1 += sv[n][f];
            }
            if (cur >= 0) atomicAdd(&pooled[cur * HID + f], s1);
        }
    } else if (i < N) {
        float4* xp = (float4*)(xcur + (i << 4));
#pragma unroll
        for (int q = 0; q < 4; ++q) xp[q] = make_float4(v[q*4+0], v[q*4+1], v[q*4+2], v[q*4+3]);
        float hr[HID];
#pragma unroll
        for (int j = 0; j < HID; ++j) hr[j] = 0.f;
#pragma unroll
        for (int k = 0; k < HID; ++k) {
            float xv = v[k];
#pragma unroll
            for (int j = 0; j < HID; ++j) hr[j] = fmaf(xv, sW[k * HID + j], hr[j]);
        }
        float a1 = 0.f, a2 = 0.f;
#pragma unroll
        for (int j = 0; j < HID; ++j) { a1 = fmaf(hr[j], sa[j], a1); a2 = fmaf(hr[j], sd[j], a2); }
        uint4* hp = (uint4*)(hb + (i << 3));
        uint4 w0, w1;
        w0.x = pack2(hr[0], hr[1]);   w0.y = pack2(hr[2], hr[3]);
        w0.z = pack2(hr[4], hr[5]);   w0.w = pack2(hr[6], hr[7]);
        w1.x = pack2(hr[8], hr[9]);   w1.y = pack2(hr[10], hr[11]);
        w1.z = pack2(hr[12], hr[13]); w1.w = pack2(hr[14], hr[15]);
        hp[0] = w0; hp[1] = w1;
        as_[i] = a1; ad_[i] = a2;
    }
}

// ---------------- final linear ----------------
__global__ void final_lin(const float* __restrict__ pooled, const float* __restrict__ gcnt,
                          const float* __restrict__ prm, const int* __restrict__ flags,
                          void* __restrict__ out) {
    int g = blockIdx.x * blockDim.x + threadIdx.x;
    if (g < NGRAPH) {
        float c = gcnt[g];
        float invc = c > 0.f ? 1.f / c : 0.f;
        float o0 = prm[1440], o1 = prm[1441];
#pragma unroll
        for (int f = 0; f < HID; ++f) {
            float p = pooled[g * HID + f] * invc;
            o0 = fmaf(p, prm[1408 + f * 2 + 0], o0);
            o1 = fmaf(p, prm[1408 + f * 2 + 1], o1);
        }
        if (flags[0]) {
            ((bf16*)out)[g * 2 + 0] = __float2bfloat16(o0);
            ((bf16*)out)[g * 2 + 1] = __float2bfloat16(o1);
        } else {
            ((float*)out)[g * 2 + 0] = o0;
            ((float*)out)[g * 2 + 1] = o1;
        }
    }
}

extern "C" void kernel_launch(void* const* d_in, const int* in_sizes, int n_in,
                              void* d_out, int out_size, void* d_ws, size_t ws_size,
                              hipStream_t stream) {
    const void* x = d_in[0];
    const int* ei = (const int*)d_in[1];
    const int* batch = (const int*)d_in[2];
    int N = in_sizes[2];
    int E = in_sizes[1] / 2;
    int din0 = in_sizes[0] / N;

    float* ws = (float*)d_ws;
    int* flags = (int*)ws;                          // 16 ints
    float* prm = ws + 16;                           // 2048 floats
    unsigned int* hb = (unsigned int*)(ws + 4096);  // N*8 u32 (bf16-packed h)
    float* t = (float*)(hb + (size_t)N * 8);        // N*16
    float* xcur = t + (size_t)N * HID;              // N*16
    float* as_ = xcur + (size_t)N * HID;            // N
    float* ad_ = as_ + N;                           // N
    int* deg = (int*)(ad_ + N);                     // N
    int* rowStart = deg + N;                        // N+1
    int* bsums = rowStart + (N + 1);                // 2048
    int* csrSrc = bsums + 2048;                     // E (+pad)
    float* gsum = (float*)(csrSrc + E + 64);        // G*16
    float* gsumsq = gsum + NGRAPH * HID;
    float* gA = gsumsq + NGRAPH * HID;
    float* gB = gA + NGRAPH * HID;
    float* pooled = gB + NGRAPH * HID;
    float* gcnt = pooled + NGRAPH * HID;
    int* seq = (int*)t;   // aliased onto t/xcur (consumed by `place` before layer 0 writes t)

    PtrPack pk;
    int n = 0;
    for (int l = 0; l < 4; ++l) {
        int dl = (l == 0) ? din0 : HID;
        int base = l * 352;
        const int offs[7] = {0, 256, 272, 288, 304, 320, 336};
        const int cnts[7] = {dl * HID, HID, HID, HID, HID, HID, HID};
        for (int j = 0; j < 7; ++j) {
            pk.src[n] = d_in[4 + l * 7 + j];
            pk.cnt[n] = cnts[j];
            pk.dstoff[n] = base + offs[j];
            ++n;
        }
    }
    pk.src[n] = d_in[32]; pk.cnt[n] = HID * 2; pk.dstoff[n] = 1408; ++n;
    pk.src[n] = d_in[33]; pk.cnt[n] = 2;       pk.dstoff[n] = 1440; ++n;
    pk.n = n;

    int nbN = (N + 255) / 256;
    int nbE = (E + 255) / 256;

    detect_k<<<1, 256, 0, stream>>>(x, ei, flags);
    cvt_params<<<1, 256, 0, stream>>>(pk, flags, prm);

    hipMemsetAsync(deg, 0, (size_t)N * sizeof(int), stream);
    hipMemsetAsync(pooled, 0, NGRAPH * HID * sizeof(float), stream);

    hist_pos<<<nbE, 256, 0, stream>>>(ei, E, flags, deg, seq);
    scan_bsum<<<nbN, 256, 0, stream>>>(deg, N, bsums);
    scan_top<<<1, 256, 0, stream>>>(bsums, nbN);
    scan_final<<<nbN, 256, 0, stream>>>(deg, bsums, N, rowStart);
    place<<<nbE, 256, 0, stream>>>(ei, E, flags, rowStart, seq, csrSrc);
    graph_cnt_k<<<(NGRAPH + 255) / 256, 256, 0, stream>>>(batch, N, gcnt);

    node_feat0<<<nbN, 256, 0, stream>>>(x, din0, flags, prm, hb, as_, ad_, N);

    for (int l = 0; l < 4; ++l) {
        const float* prmL = prm + l * 352;
        const float* prmNext = prm + (l + 1 < 4 ? (l + 1) * 352 : 0);

        hipMemsetAsync(gsum, 0, 2 * NGRAPH * HID * sizeof(float), stream);
        gat_agg<<<nbN, 256, 0, stream>>>(rowStart, csrSrc, hb, as_, ad_, prmL, batch,
                                         t, gsum, gsumsq, N);
        norm_coef<<<(NGRAPH * HID + 255) / 256, 256, 0, stream>>>(gsum, gsumsq, gcnt, prmL, gA, gB);
        norm_feat<<<nbN, 256, 0, stream>>>(t, gA, gB, batch, xcur, N, l > 0 ? 1 : 0,
                                           l == 3 ? 1 : 0, prmNext, hb, as_, ad_, pooled);
    }

    final_lin<<<(NGRAPH + 255) / 256, 256, 0, stream>>>(pooled, gcnt, prm, flags, d_out);
}

// Round 6
// 1069.804 us; speedup vs baseline: 1.4623x; 1.1313x over previous
//
#include <hip/hip_runtime.h>
#include <hip/hip_bf16.h>

#define HID 16
#define NGRAPH 1000
#define NEG_SLOPE 0.2f
#define EPS_GN 1e-5f
#define BSH 11              // bucket shift: 2048 dsts per bucket
#define BS 2048             // bucket span (power of 2)
#define NBMAX 2048
#define CHK 4096            // edges per scatter chunk

typedef __hip_bfloat16 bf16;

static __device__ __forceinline__ float b2f(bf16 v) { return __bfloat162float(v); }

// pack two floats into one u32 holding two RNE-rounded bf16s (a=low, b=high)
static __device__ __forceinline__ unsigned int pack2(float a, float b) {
    unsigned int ia = __float_as_uint(a);
    unsigned int ib = __float_as_uint(b);
    ia += 0x7FFFu + ((ia >> 16) & 1u);
    ib += 0x7FFFu + ((ib >> 16) & 1u);
    return (ia >> 16) | (ib & 0xFFFF0000u);
}

// acc[0..15] += p * bf16row(ra,rb)
static __device__ __forceinline__ void fma_row(const uint4 ra, const uint4 rb, float p,
                                               float* __restrict__ acc) {
    unsigned int us[8] = {ra.x, ra.y, ra.z, ra.w, rb.x, rb.y, rb.z, rb.w};
#pragma unroll
    for (int q = 0; q < 8; ++q) {
        float lo = __uint_as_float(us[q] << 16);
        float hi = __uint_as_float(us[q] & 0xFFFF0000u);
        acc[2 * q]     = fmaf(p, lo, acc[2 * q]);
        acc[2 * q + 1] = fmaf(p, hi, acc[2 * q + 1]);
    }
}

struct PtrPack { const void* src[30]; int cnt[30]; int dstoff[30]; int n; };

// ---------------- dtype detection ----------------
__global__ void detect_k(const void* x, const void* ei, int* flags) {
    __shared__ int cbf, czero;
    int t = threadIdx.x;
    if (t == 0) { cbf = 0; czero = 0; }
    __syncthreads();
    const unsigned int* xw = (const unsigned int*)x;
    unsigned int w = xw[t * 4];
    int e_lo = (int)((w >> 7) & 0xFF);
    if (e_lo >= 100 && e_lo <= 140) atomicAdd(&cbf, 1);
    const unsigned int* ew = (const unsigned int*)ei;
    if (ew[2 * t + 1] == 0u) atomicAdd(&czero, 1);
    __syncthreads();
    if (t == 0) {
        flags[0] = (cbf >= 192) ? 1 : 0;
        flags[1] = (czero >= 250) ? 1 : 0;
    }
}

__global__ void cvt_params(PtrPack pk, const int* __restrict__ flags, float* __restrict__ dst) {
    int isb = flags[0];
    for (int j = 0; j < pk.n; ++j) {
        const void* s = pk.src[j];
        int c = pk.cnt[j], o = pk.dstoff[j];
        for (int i = threadIdx.x; i < c; i += blockDim.x) {
            float v = isb ? b2f(((const bf16*)s)[i]) : ((const float*)s)[i];
            dst[o + i] = v;
        }
    }
}

static __device__ __forceinline__ int ld_src(const int* ei, int E, int e, int i64) {
    return i64 ? ei[2ll * e] : ei[e];
}
static __device__ __forceinline__ int ld_dst(const int* ei, int E, int e, int i64) {
    return i64 ? ei[2ll * (E + e)] : ei[(long long)E + e];
}

// ---------------- CSR build: two-level bucket counting sort ----------------

// Pass A: per-bucket edge counts (LDS-aggregated)
__global__ void bucket_count(const int* __restrict__ ei, int E, const int* __restrict__ flags,
                             int* __restrict__ bcnt, int NB) {
    __shared__ int lh[NBMAX];
    int tid = threadIdx.x;
    for (int i = tid; i < NB; i += 256) lh[i] = 0;
    __syncthreads();
    int i64 = flags[1];
    int stride = gridDim.x * 256;
    for (int e = blockIdx.x * 256 + tid; e < E; e += stride)
        atomicAdd(&lh[ld_dst(ei, E, e, i64) >> BSH], 1);
    __syncthreads();
    for (int i = tid; i < NB; i += 256)
        if (lh[i]) atomicAdd(&bcnt[i], lh[i]);
}

// exclusive scan of bucket counts -> gBase[0..NB] (gBase[NB]=E), gCursor copy; rowStart[N]=E
__global__ void scan_buckets(const int* __restrict__ bcnt, int NB, int E,
                             int* __restrict__ gBase, int* __restrict__ gCursor,
                             int* __restrict__ rowStart, int N) {
    __shared__ int part[256];
    int t = threadIdx.x;
    int per = (NB + 255) >> 8;
    int lo = t * per, hi = min(lo + per, NB);
    int s = 0;
    for (int i = lo; i < hi; ++i) s += bcnt[i];
    part[t] = s;
    __syncthreads();
    for (int off = 1; off < 256; off <<= 1) {
        int v = (t >= off) ? part[t - off] : 0;
        __syncthreads();
        part[t] += v;
        __syncthreads();
    }
    int acc = (t == 0) ? 0 : part[t - 1];
    for (int i = lo; i < hi; ++i) {
        gBase[i] = acc; gCursor[i] = acc;
        acc += bcnt[i];
    }
    if (t == 0) { gBase[NB] = E; rowStart[N] = E; }
}

// Pass B: scatter edges into bucket-contiguous (src, dstLow) pairs
__global__ void bucket_scatter(const int* __restrict__ ei, int E, const int* __restrict__ flags,
                               int* __restrict__ gCursor, uint2* __restrict__ binned, int NB) {
    __shared__ int lh[NBMAX];
    __shared__ int lbase[NBMAX];
    __shared__ int lcur[NBMAX];
    int tid = threadIdx.x;
    int i64 = flags[1];
    int nchunk = (E + CHK - 1) / CHK;
    for (int chunk = blockIdx.x; chunk < nchunk; chunk += gridDim.x) {
        int c0 = chunk * CHK;
        int c1 = min(c0 + CHK, E);
        for (int i = tid; i < NB; i += 256) lh[i] = 0;
        __syncthreads();
        for (int e = c0 + tid; e < c1; e += 256)
            atomicAdd(&lh[ld_dst(ei, E, e, i64) >> BSH], 1);
        __syncthreads();
        for (int b = tid; b < NB; b += 256) {
            int c = lh[b];
            lbase[b] = c ? atomicAdd(&gCursor[b], c) : 0;
            lcur[b] = 0;
        }
        __syncthreads();
        for (int e = c0 + tid; e < c1; e += 256) {
            int d = ld_dst(ei, E, e, i64);
            int s = ld_src(ei, E, e, i64);
            int b = d >> BSH;
            int off = atomicAdd(&lcur[b], 1);
            binned[lbase[b] + off] = make_uint2((unsigned)s, (unsigned)(d & (BS - 1)));
        }
        __syncthreads();
    }
}

// Pass C: per-bucket counting sort in LDS -> csrSrc + rowStart
__global__ void bucket_sort(const uint2* __restrict__ binned, const int* __restrict__ gBase,
                            int* __restrict__ csrSrc, int* __restrict__ rowStart, int N) {
    __shared__ int hist[BS];
    __shared__ int tsum[1024];
    int tid = threadIdx.x;
    int b = blockIdx.x;
    int base = gBase[b];
    int cnt = gBase[b + 1] - base;
    for (int i = tid; i < BS; i += 1024) hist[i] = 0;
    __syncthreads();
    for (int i = tid; i < cnt; i += 1024)
        atomicAdd(&hist[binned[base + i].y], 1);
    __syncthreads();
    int a0 = hist[2 * tid], a1 = hist[2 * tid + 1];
    tsum[tid] = a0 + a1;
    __syncthreads();
    for (int off = 1; off < 1024; off <<= 1) {
        int v = (tid >= off) ? tsum[tid - off] : 0;
        __syncthreads();
        tsum[tid] += v;
        __syncthreads();
    }
    int excl = (tid == 0) ? 0 : tsum[tid - 1];
    int d0 = b * BS + 2 * tid;
    if (d0 < N) rowStart[d0] = base + excl;
    if (d0 + 1 < N) rowStart[d0 + 1] = base + excl + a0;
    __syncthreads();
    hist[2 * tid] = excl;
    hist[2 * tid + 1] = excl + a0;
    __syncthreads();
    for (int i = tid; i < cnt; i += 1024) {
        uint2 pr = binned[base + i];
        int off = atomicAdd(&hist[pr.y], 1);
        csrSrc[base + off] = (int)pr.x;
    }
}

__global__ void graph_cnt_k(const int* __restrict__ batch, int N, float* __restrict__ gcnt) {
    int g = blockIdx.x * blockDim.x + threadIdx.x;
    if (g < NGRAPH) {
        int lo = 0, hi = N;
        while (lo < hi) { int mid = (lo + hi) >> 1; if (batch[mid] < g) lo = mid + 1; else hi = mid; }
        int lb = lo;
        lo = 0; hi = N;
        while (lo < hi) { int mid = (lo + hi) >> 1; if (batch[mid] <= g) lo = mid + 1; else hi = mid; }
        gcnt[g] = (float)(lo - lb);
    }
}

// ---------------- layer-0 node transform (writes bf16-packed h) ----------------
__global__ void node_feat0(const void* __restrict__ xin, int din,
                           const int* __restrict__ flags, const float* __restrict__ prmL,
                           unsigned int* __restrict__ hb, float* __restrict__ as_,
                           float* __restrict__ ad_, int N) {
    __shared__ float sW[256], sa[HID], sd[HID];
    int t = threadIdx.x;
    if (t < din * HID) sW[t] = prmL[t];
    if (t < HID) { sa[t] = prmL[256 + t]; sd[t] = prmL[272 + t]; }
    __syncthreads();
    int i = blockIdx.x * blockDim.x + t;
    if (i >= N) return;
    int isb = flags[0];
    const float* xf = (const float*)xin;
    const bf16* xb = (const bf16*)xin;
    float hr[HID];
#pragma unroll
    for (int j = 0; j < HID; ++j) hr[j] = 0.f;
    int base = i * din;
    for (int k = 0; k < din; ++k) {
        float xv = isb ? b2f(xb[base + k]) : xf[base + k];
#pragma unroll
        for (int j = 0; j < HID; ++j) hr[j] = fmaf(xv, sW[k * HID + j], hr[j]);
    }
    float a1 = 0.f, a2 = 0.f;
#pragma unroll
    for (int j = 0; j < HID; ++j) { a1 = fmaf(hr[j], sa[j], a1); a2 = fmaf(hr[j], sd[j], a2); }
    uint4* hp = (uint4*)(hb + (i << 3));
    uint4 w0, w1;
    w0.x = pack2(hr[0], hr[1]);   w0.y = pack2(hr[2], hr[3]);
    w0.z = pack2(hr[4], hr[5]);   w0.w = pack2(hr[6], hr[7]);
    w1.x = pack2(hr[8], hr[9]);   w1.y = pack2(hr[10], hr[11]);
    w1.z = pack2(hr[12], hr[13]); w1.w = pack2(hr[14], hr[15]);
    hp[0] = w0; hp[1] = w1;
    as_[i] = a1; ad_[i] = a2;
}

// ---------------- GAT aggregation: lane-per-node, chunk-4 MLP, bf16 h gathers ----------------
__global__ void __launch_bounds__(256, 4)
gat_agg(const int* __restrict__ rowStart, const int* __restrict__ csrSrc,
        const unsigned int* __restrict__ hb, const float* __restrict__ as_,
        const float* __restrict__ ad_, const float* __restrict__ prmL,
        const int* __restrict__ batch,
        float* __restrict__ t_out, float* __restrict__ gsum,
        float* __restrict__ gsumsq, int N) {
    __shared__ float sv[256][HID + 1];
    __shared__ int sg[256];
    int tid = threadIdx.x;
    int node = blockIdx.x * 256 + tid;
    bool valid = node < N;
    float acc[HID];
    float tv[HID];
    int g = -1;
    if (valid) {
        int start = rowStart[node];
        int end = rowStart[node + 1];
        float adi = ad_[node];
        float zs = as_[node] + adi;
        float e_self = zs > 0.f ? zs : NEG_SLOPE * zs;
        float m = e_self, ssum = 0.f;
#pragma unroll
        for (int f = 0; f < HID; ++f) acc[f] = 0.f;
        for (int base = start; base < end; base += 4) {
            bool v1 = base + 1 < end, v2 = base + 2 < end, v3 = base + 3 < end;
            int s0 = csrSrc[base];
            int s1 = v1 ? csrSrc[base + 1] : s0;
            int s2 = v2 ? csrSrc[base + 2] : s0;
            int s3 = v3 ? csrSrc[base + 3] : s0;
            float a0 = as_[s0], a1 = as_[s1], a2 = as_[s2], a3 = as_[s3];
            const uint4* h0 = (const uint4*)(hb + (s0 << 3));
            const uint4* h1 = (const uint4*)(hb + (s1 << 3));
            const uint4* h2 = (const uint4*)(hb + (s2 << 3));
            const uint4* h3 = (const uint4*)(hb + (s3 << 3));
            uint4 r00 = h0[0], r01 = h0[1];
            uint4 r10 = h1[0], r11 = h1[1];
            uint4 r20 = h2[0], r21 = h2[1];
            uint4 r30 = h3[0], r31 = h3[1];
            float z0 = a0 + adi, z1 = a1 + adi, z2 = a2 + adi, z3 = a3 + adi;
            float e0 = z0 > 0.f ? z0 : NEG_SLOPE * z0;
            float e1 = v1 ? (z1 > 0.f ? z1 : NEG_SLOPE * z1) : -1e30f;
            float e2 = v2 ? (z2 > 0.f ? z2 : NEG_SLOPE * z2) : -1e30f;
            float e3 = v3 ? (z3 > 0.f ? z3 : NEG_SLOPE * z3) : -1e30f;
            float cm = fmaxf(fmaxf(e0, e1), fmaxf(e2, e3));
            if (cm > m) {
                float sc = __expf(m - cm);
                ssum *= sc;
#pragma unroll
                for (int f = 0; f < HID; ++f) acc[f] *= sc;
                m = cm;
            }
            float p0 = __expf(e0 - m);
            float p1 = v1 ? __expf(e1 - m) : 0.f;
            float p2 = v2 ? __expf(e2 - m) : 0.f;
            float p3 = v3 ? __expf(e3 - m) : 0.f;
            ssum += p0 + p1 + p2 + p3;
            fma_row(r00, r01, p0, acc);
            fma_row(r10, r11, p1, acc);
            fma_row(r20, r21, p2, acc);
            fma_row(r30, r31, p3, acc);
        }
        const uint4* hs = (const uint4*)(hb + (node << 3));
        uint4 rs0 = hs[0], rs1 = hs[1];
        float pself = __expf(e_self - m);
        ssum += pself;
        fma_row(rs0, rs1, pself, acc);
        float inv = 1.f / ssum;
#pragma unroll
        for (int f = 0; f < HID; ++f) tv[f] = fmaf(acc[f], inv, prmL[288 + f]);
        float4* tp = (float4*)(t_out + (node << 4));
        tp[0] = make_float4(tv[0], tv[1], tv[2], tv[3]);
        tp[1] = make_float4(tv[4], tv[5], tv[6], tv[7]);
        tp[2] = make_float4(tv[8], tv[9], tv[10], tv[11]);
        tp[3] = make_float4(tv[12], tv[13], tv[14], tv[15]);
        g = batch[node];
    }
    sg[tid] = valid ? g : -1;
#pragma unroll
    for (int f = 0; f < HID; ++f) sv[tid][f] = valid ? tv[f] : 0.f;
    __syncthreads();
    if (tid < 64) {
        int f = tid & 15;
        int seg = tid >> 4;
        int n0 = seg * 64, n1 = n0 + 64;
        float s1 = 0.f, s2 = 0.f;
        int cur = -2;
        for (int n = n0; n < n1; ++n) {
            int bg = sg[n];
            if (bg < 0) continue;
            if (bg != cur) {
                if (cur >= 0) { atomicAdd(&gsum[cur * HID + f], s1); atomicAdd(&gsumsq[cur * HID + f], s2); }
                cur = bg; s1 = 0.f; s2 = 0.f;
            }
            float v = sv[n][f];
            s1 += v; s2 += v * v;
        }
        if (cur >= 0) { atomicAdd(&gsum[cur * HID + f], s1); atomicAdd(&gsumsq[cur * HID + f], s2); }
    }
}

// ---------------- GraphNorm coefficients ----------------
__global__ void norm_coef(const float* __restrict__ gsum, const float* __restrict__ gsumsq,
                          const float* __restrict__ gcnt, const float* __restrict__ prmL,
                          float* __restrict__ A, float* __restrict__ B) {
    int idx = blockIdx.x * blockDim.x + threadIdx.x;
    if (idx < NGRAPH * HID) {
        int g = idx >> 4, f = idx & 15;
        float c = gcnt[g];
        float invc = c > 0.f ? 1.f / c : 0.f;
        float mean = gsum[idx] * invc;
        float msq = gsumsq[idx] * invc;
        float gaf = prmL[336 + f];
        float var = msq + (gaf * gaf - 2.f * gaf) * mean * mean;
        var = fmaxf(var, 0.f);
        float inv = rsqrtf(var + EPS_GN);
        float Af = prmL[304 + f] * inv;
        A[idx] = Af;
        B[idx] = prmL[320 + f] - Af * gaf * mean;
    }
}

// ---------------- fused norm+relu(+residual) + next-layer features / final pool ----------------
__global__ void norm_feat(const float* __restrict__ t_in, const float* __restrict__ gA,
                          const float* __restrict__ gB, const int* __restrict__ batch,
                          float* __restrict__ xcur, int N, int residual, int isLast,
                          const float* __restrict__ prmNext,
                          unsigned int* __restrict__ hb, float* __restrict__ as_,
                          float* __restrict__ ad_, float* __restrict__ pooled) {
    __shared__ float sW[256], sa[HID], sd[HID];
    __shared__ float sv[256][HID + 1];
    __shared__ int sg[256];
    int tid = threadIdx.x;
    if (!isLast) {
        sW[tid] = prmNext[tid];
        if (tid < HID) { sa[tid] = prmNext[256 + tid]; sd[tid] = prmNext[272 + tid]; }
        __syncthreads();
    }
    int i = blockIdx.x * 256 + tid;
    float v[HID];
    int g = -1;
    if (i < N) {
        g = batch[i];
        const float* Ar = gA + g * HID;
        const float* Br = gB + g * HID;
        const float4* tp = (const float4*)(t_in + (i << 4));
        float4 xr[4];
        if (residual) {
            const float4* xp = (const float4*)(xcur + (i << 4));
#pragma unroll
            for (int q = 0; q < 4; ++q) xr[q] = xp[q];
        } else {
#pragma unroll
            for (int q = 0; q < 4; ++q) xr[q] = make_float4(0.f, 0.f, 0.f, 0.f);
        }
#pragma unroll
        for (int q = 0; q < 4; ++q) {
            float4 t4 = tp[q];
            float ts[4] = {t4.x, t4.y, t4.z, t4.w};
            float xs[4] = {xr[q].x, xr[q].y, xr[q].z, xr[q].w};
#pragma unroll
            for (int c = 0; c < 4; ++c) {
                int f = q * 4 + c;
                float val = fmaf(Ar[f], ts[c], Br[f]) + xs[c];
                v[f] = fmaxf(val, 0.f);
            }
        }
    }
    if (isLast) {
        sg[tid] = (i < N) ? g : -1;
#pragma unroll
        for (int f = 0; f < HID; ++f) sv[tid][f] = (i < N) ? v[f] : 0.f;
        __syncthreads();
        if (tid < 64) {
            int f = tid & 15;
            int seg = tid >> 4;
            int n0 = seg * 64, n1 = n0 + 64;
            float s1 = 0.f;
            int cur = -2;
            for (int n = n0; n < n1; ++n) {
                int bg = sg[n];
                if (bg < 0) continue;
                if (bg != cur) { if (cur >= 0) atomicAdd(&pooled[cur * HID + f], s1); cur = bg; s1 = 0.f; }
                s1 += sv[n][f];
            }
            if (cur >= 0) atomicAdd(&pooled[cur * HID + f], s1);
        }
    } else if (i < N) {
        float4* xp = (float4*)(xcur + (i << 4));
#pragma unroll
        for (int q = 0; q < 4; ++q) xp[q] = make_float4(v[q*4+0], v[q*4+1], v[q*4+2], v[q*4+3]);
        float hr[HID];
#pragma unroll
        for (int j = 0; j < HID; ++j) hr[j] = 0.f;
#pragma unroll
        for (int k = 0; k < HID; ++k) {
            float xv = v[k];
#pragma unroll
            for (int j = 0; j < HID; ++j) hr[j] = fmaf(xv, sW[k * HID + j], hr[j]);
        }
        float a1 = 0.f, a2 = 0.f;
#pragma unroll
        for (int j = 0; j < HID; ++j) { a1 = fmaf(hr[j], sa[j], a1); a2 = fmaf(hr[j], sd[j], a2); }
        uint4* hp = (uint4*)(hb + (i << 3));
        uint4 w0, w1;
        w0.x = pack2(hr[0], hr[1]);   w0.y = pack2(hr[2], hr[3]);
        w0.z = pack2(hr[4], hr[5]);   w0.w = pack2(hr[6], hr[7]);
        w1.x = pack2(hr[8], hr[9]);   w1.y = pack2(hr[10], hr[11]);
        w1.z = pack2(hr[12], hr[13]); w1.w = pack2(hr[14], hr[15]);
        hp[0] = w0; hp[1] = w1;
        as_[i] = a1; ad_[i] = a2;
    }
}

// ---------------- final linear ----------------
__global__ void final_lin(const float* __restrict__ pooled, const float* __restrict__ gcnt,
                          const float* __restrict__ prm, const int* __restrict__ flags,
                          void* __restrict__ out) {
    int g = blockIdx.x * blockDim.x + threadIdx.x;
    if (g < NGRAPH) {
        float c = gcnt[g];
        float invc = c > 0.f ? 1.f / c : 0.f;
        float o0 = prm[1440], o1 = prm[1441];
#pragma unroll
        for (int f = 0; f < HID; ++f) {
            float p = pooled[g * HID + f] * invc;
            o0 = fmaf(p, prm[1408 + f * 2 + 0], o0);
            o1 = fmaf(p, prm[1408 + f * 2 + 1], o1);
        }
        if (flags[0]) {
            ((bf16*)out)[g * 2 + 0] = __float2bfloat16(o0);
            ((bf16*)out)[g * 2 + 1] = __float2bfloat16(o1);
        } else {
            ((float*)out)[g * 2 + 0] = o0;
            ((float*)out)[g * 2 + 1] = o1;
        }
    }
}

extern "C" void kernel_launch(void* const* d_in, const int* in_sizes, int n_in,
                              void* d_out, int out_size, void* d_ws, size_t ws_size,
                              hipStream_t stream) {
    const void* x = d_in[0];
    const int* ei = (const int*)d_in[1];
    const int* batch = (const int*)d_in[2];
    int N = in_sizes[2];
    int E = in_sizes[1] / 2;
    int din0 = in_sizes[0] / N;
    int NB = (N + BS - 1) / BS;   // <= NBMAX for N <= 4.19M

    float* ws = (float*)d_ws;
    int* flags = (int*)ws;                          // 16 ints
    float* prm = ws + 16;                           // 2048 floats
    unsigned int* hb = (unsigned int*)(ws + 4096);  // N*8 u32 (bf16-packed h)
    float* t = (float*)(hb + (size_t)N * 8);        // N*16
    float* xcur = t + (size_t)N * HID;              // N*16
    float* as_ = xcur + (size_t)N * HID;            // N
    float* ad_ = as_ + N;                           // N
    int* rowStart = (int*)(ad_ + N);                // N+1
    int* bcnt = rowStart + (N + 1);                 // NBMAX
    int* gBase = bcnt + NBMAX;                      // NBMAX+1
    int* gCursor = gBase + NBMAX + 1;               // NBMAX
    int* csrSrc = gCursor + NBMAX;                  // E (+pad)
    float* gsum = (float*)(csrSrc + E + 64);        // G*16
    float* gsumsq = gsum + NGRAPH * HID;
    float* gA = gsumsq + NGRAPH * HID;
    float* gB = gA + NGRAPH * HID;
    float* pooled = gB + NGRAPH * HID;
    float* gcnt = pooled + NGRAPH * HID;
    uint2* binned = (uint2*)t;   // E*8B, aliases t(+xcur); dead before layer 0 writes t

    PtrPack pk;
    int n = 0;
    for (int l = 0; l < 4; ++l) {
        int dl = (l == 0) ? din0 : HID;
        int base = l * 352;
        const int offs[7] = {0, 256, 272, 288, 304, 320, 336};
        const int cnts[7] = {dl * HID, HID, HID, HID, HID, HID, HID};
        for (int j = 0; j < 7; ++j) {
            pk.src[n] = d_in[4 + l * 7 + j];
            pk.cnt[n] = cnts[j];
            pk.dstoff[n] = base + offs[j];
            ++n;
        }
    }
    pk.src[n] = d_in[32]; pk.cnt[n] = HID * 2; pk.dstoff[n] = 1408; ++n;
    pk.src[n] = d_in[33]; pk.cnt[n] = 2;       pk.dstoff[n] = 1440; ++n;
    pk.n = n;

    int nbN = (N + 255) / 256;

    detect_k<<<1, 256, 0, stream>>>(x, ei, flags);
    cvt_params<<<1, 256, 0, stream>>>(pk, flags, prm);

    hipMemsetAsync(bcnt, 0, NBMAX * sizeof(int), stream);
    hipMemsetAsync(pooled, 0, NGRAPH * HID * sizeof(float), stream);

    bucket_count<<<1024, 256, 0, stream>>>(ei, E, flags, bcnt, NB);
    scan_buckets<<<1, 256, 0, stream>>>(bcnt, NB, E, gBase, gCursor, rowStart, N);
    bucket_scatter<<<1024, 256, 0, stream>>>(ei, E, flags, gCursor, binned, NB);
    bucket_sort<<<NB, 1024, 0, stream>>>(binned, gBase, csrSrc, rowStart, N);
    graph_cnt_k<<<(NGRAPH + 255) / 256, 256, 0, stream>>>(batch, N, gcnt);

    node_feat0<<<nbN, 256, 0, stream>>>(x, din0, flags, prm, hb, as_, ad_, N);

    for (int l = 0; l < 4; ++l) {
        const float* prmL = prm + l * 352;
        const float* prmNext = prm + (l + 1 < 4 ? (l + 1) * 352 : 0);

        hipMemsetAsync(gsum, 0, 2 * NGRAPH * HID * sizeof(float), stream);
        gat_agg<<<nbN, 256, 0, stream>>>(rowStart, csrSrc, hb, as_, ad_, prmL, batch,
                                         t, gsum, gsumsq, N);
        norm_coef<<<(NGRAPH * HID + 255) / 256, 256, 0, stream>>>(gsum, gsumsq, gcnt, prmL, gA, gB);
        norm_feat<<<nbN, 256, 0, stream>>>(t, gA, gB, batch, xcur, N, l > 0 ? 1 : 0,
                                           l == 3 ? 1 : 0, prmNext, hb, as_, ad_, pooled);
    }

    final_lin<<<(NGRAPH + 255) / 256, 256, 0, stream>>>(pooled, gcnt, prm, flags, d_out);
}